// Round 6
// baseline (1340.376 us; speedup 1.0000x reference)
//
#include <hip/hip_runtime.h>

constexpr int NN = 50000;     // nodes
constexpr int NE = 800000;    // edges
constexpr float SLOPE_A = 0.2f;   // attention leaky_relu
constexpr float SLOPE_R = 0.01f;  // activation leaky_relu
constexpr int SCB = 196;      // scan blocks: 196*256 = 50176 >= NN

typedef __attribute__((ext_vector_type(8))) short bf16x8;
typedef __attribute__((ext_vector_type(4))) float f32x4;

__device__ __forceinline__ unsigned short f2bf(float f) {
    union { float f; unsigned u; } v; v.f = f;
    unsigned u = v.u;
    unsigned r = u + 0x7fffu + ((u >> 16) & 1u);  // round-to-nearest-even
    return (unsigned short)(r >> 16);
}
__device__ __forceinline__ float bf2f(unsigned short s) {
    union { unsigned u; float f; } v; v.u = ((unsigned)s) << 16;
    return v.f;
}
// low/high bf16 halves of a packed u32 -> f32 (1 VALU op each)
__device__ __forceinline__ float bflo(unsigned u) {
    union { unsigned u; float f; } v; v.u = u << 16; return v.f;
}
__device__ __forceinline__ float bfhi(unsigned u) {
    union { unsigned u; float f; } v; v.u = u & 0xffff0000u; return v.f;
}

// ---------------- CSR build ----------------
__global__ void k_hist(const int* __restrict__ dst, int* __restrict__ cnt) {
    int i = blockIdx.x * 256 + threadIdx.x;
    if (i < NE) atomicAdd(&cnt[dst[i]], 1);
}

__global__ void k_scan1(const int* __restrict__ cnt, int* __restrict__ loc,
                        int* __restrict__ bsum) {
    __shared__ int sh[256];
    int t = threadIdx.x;
    int i = blockIdx.x * 256 + t;
    int v = (i < NN) ? cnt[i] : 0;
    sh[t] = v;
    __syncthreads();
    for (int off = 1; off < 256; off <<= 1) {
        int tmp = (t >= off) ? sh[t - off] : 0;
        __syncthreads();
        sh[t] += tmp;
        __syncthreads();
    }
    loc[i] = sh[t] - v;
    if (t == 255) bsum[blockIdx.x] = sh[255];
}

__global__ void k_scan2(const int* __restrict__ bsum, int* __restrict__ boff,
                        int* __restrict__ rowptr) {
    __shared__ int sh[256];
    int t = threadIdx.x;
    int v = (t < SCB) ? bsum[t] : 0;
    sh[t] = v;
    __syncthreads();
    for (int off = 1; off < 256; off <<= 1) {
        int tmp = (t >= off) ? sh[t - off] : 0;
        __syncthreads();
        sh[t] += tmp;
        __syncthreads();
    }
    if (t < SCB) boff[t] = sh[t] - v;
    if (t == 255) rowptr[NN] = sh[255];
}

__global__ void k_scan3(const int* __restrict__ loc, const int* __restrict__ boff,
                        int* __restrict__ rowptr, int* __restrict__ cursor) {
    int i = blockIdx.x * 256 + threadIdx.x;
    if (i < NN) {
        int r = loc[i] + boff[blockIdx.x];
        rowptr[i] = r;
        cursor[i] = r;
    }
}

// src ids fit in 16 bits (NN < 65536)
__global__ void k_scatter(const int* __restrict__ src, const int* __restrict__ dst,
                          int* __restrict__ cursor, unsigned short* __restrict__ ssrc) {
    int i = blockIdx.x * 256 + threadIdx.x;
    if (i < NE) {
        int d = dst[i];
        int pos = atomicAdd(&cursor[d], 1);
        ssrc[pos] = (unsigned short)src[i];
    }
}

// ---------------- fold: Wfrag + cvec + wl/wr fragment + offlr, all from fp32 W ----
__global__ void k_fold(const float* __restrict__ W, const float* __restrict__ sc,
                       const float* __restrict__ sh, const float* __restrict__ al,
                       const float* __restrict__ ar, unsigned short* __restrict__ Wfrag,
                       float* __restrict__ cvec, unsigned short* __restrict__ wlrfrag,
                       float* __restrict__ offlr, int has_bn) {
    int b = blockIdx.x;
    if (b < 32) {
        int gid = b * 256 + threadIdx.x;   // < 8192; one thread = 8 shorts
        int lane = gid & 63;
        int frag = gid >> 6;               // 0..127
        int j = frag & 3, kc = (frag >> 2) & 7, w = frag >> 5;
        int mm = lane & 15, q = lane >> 4;
        int n = 64 * w + 16 * j + mm;
        int k0 = kc * 32 + q * 8;
        unsigned short o[8];
#pragma unroll
        for (int t = 0; t < 8; t++) {
            float wv = W[(size_t)(k0 + t) * 256 + n];
            if (sc) wv *= sc[k0 + t];
            o[t] = f2bf(wv);
        }
        *(uint4*)(Wfrag + (size_t)gid * 8) = *(const uint4*)o;
    } else if (has_bn && b < 288) {
        __shared__ float red[256];
        int n = b - 32, k = threadIdx.x;
        red[k] = sh[k] * W[(size_t)k * 256 + n];
        __syncthreads();
        for (int off = 128; off > 0; off >>= 1) {
            if (k < off) red[k] += red[k + off];
            __syncthreads();
        }
        if (k == 0) cvec[n] = red[0];
    } else {
        int n = b - (has_bn ? 288 : 32);   // 0..7
        int h = n >> 1;
        const float* a = (n & 1) ? ar : al;
        int k = threadIdx.x;
        float raw = 0.f;
#pragma unroll 8
        for (int d = 0; d < 64; d++)
            raw += W[(size_t)k * 256 + 64 * h + d] * a[h * 64 + d];
        float val = (sc ? sc[k] : 1.f) * raw;
        int kc = k >> 5, rem = k & 31, q = rem >> 3, t = rem & 7;  // k = kc*32+q*8+t
        wlrfrag[kc * 512 + (q * 16 + n) * 8 + t] = f2bf(val);
        wlrfrag[kc * 512 + (q * 16 + n + 8) * 8 + t] = 0;   // zero the unused col
        __shared__ float red[256];
        red[k] = sh ? sh[k] * raw : 0.f;
        __syncthreads();
        for (int off = 128; off > 0; off >>= 1) {
            if (k < off) red[k] += red[k + off];
            __syncthreads();
        }
        if (k == 0) offlr[n] = red[0];
    }
}

// ---------------- GEMM: feat = A @ Wfrag (+cvec); el/er via extra MFMA --------
// feat16 written SLICE-MAJOR [slice=ch/32][node][32ch] so each XCD's gather set
// in k_aggx is a contiguous 3.2 MB region (L2-resident). el/er head-major.
__launch_bounds__(256)
__global__ void k_gemm(const void* __restrict__ Araw, int af32,
                       const unsigned short* __restrict__ Wfrag,
                       const float* __restrict__ cvec,
                       const unsigned short* __restrict__ wlrfrag,
                       const float* __restrict__ offlr,
                       unsigned short* __restrict__ feat16, float* __restrict__ el,
                       float* __restrict__ er) {
    constexpr int AP = 264;  // A lds pitch in bf16 elems (row start 16B-aligned)
    __shared__ __align__(16) unsigned short Alds[64 * AP];
    const int tid = threadIdx.x;
    const int rowbase = blockIdx.x * 64;

    // stage A: 64 rows x 256 bf16
    if (af32) {
        const float* A = (const float*)Araw;
        int r = tid >> 6;
        int c4 = tid & 63;
        for (int it = 0; it < 16; it++) {
            int rr = it * 4 + r;
            int gr = rowbase + rr;
            float4 v = make_float4(0.f, 0.f, 0.f, 0.f);
            if (gr < NN) v = *(const float4*)(A + (size_t)gr * 256 + c4 * 4);
            ushort4 pv;
            pv.x = f2bf(v.x); pv.y = f2bf(v.y); pv.z = f2bf(v.z); pv.w = f2bf(v.w);
            *(ushort4*)(&Alds[rr * AP + c4 * 4]) = pv;
        }
    } else {
        const unsigned short* A = (const unsigned short*)Araw;
        for (int it = 0; it < 8; it++) {
            int idx = it * 256 + tid;
            int rr = idx >> 5;
            int c16 = idx & 31;
            int gr = rowbase + rr;
            uint4 v = make_uint4(0u, 0u, 0u, 0u);
            if (gr < NN) v = *(const uint4*)(A + (size_t)gr * 256 + c16 * 8);
            *(uint4*)(&Alds[rr * AP + c16 * 8]) = v;
        }
    }
    __syncthreads();

    f32x4 acc[4][4];
    for (int i = 0; i < 4; i++)
        for (int j = 0; j < 4; j++)
            acc[i][j] = (f32x4){0.f, 0.f, 0.f, 0.f};
    f32x4 accLR[4];
    for (int i = 0; i < 4; i++) accLR[i] = (f32x4){0.f, 0.f, 0.f, 0.f};

    const int lane = tid & 63, w = tid >> 6;
    const int mm = lane & 15, q = lane >> 4;

    const unsigned short* bbase = Wfrag + ((size_t)w * 8 * 4) * 512 + (size_t)lane * 8;

#pragma unroll
    for (int kc = 0; kc < 8; kc++) {
        bf16x8 a[4], b[4];
        for (int i = 0; i < 4; i++)
            a[i] = *(const bf16x8*)(&Alds[(16 * i + mm) * AP + kc * 32 + q * 8]);
        for (int j = 0; j < 4; j++)
            b[j] = *(const bf16x8*)(bbase + (size_t)(kc * 4 + j) * 512);
        for (int i = 0; i < 4; i++)
            for (int j = 0; j < 4; j++)
                acc[i][j] = __builtin_amdgcn_mfma_f32_16x16x32_bf16(a[i], b[j], acc[i][j], 0, 0, 0);
        if (w == 0) {
            bf16x8 blr = *(const bf16x8*)(wlrfrag + kc * 512 + lane * 8);
            for (int i = 0; i < 4; i++)
                accLR[i] = __builtin_amdgcn_mfma_f32_16x16x32_bf16(a[i], blr, accLR[i], 0, 0, 0);
        }
    }
    __syncthreads();   // all waves done reading Alds before epilogue reuses it

    // ---- folded-BN column offset on feat ----
    if (cvec) {
        float cv[4];
        for (int j = 0; j < 4; j++) cv[j] = cvec[64 * w + 16 * j + mm];
        for (int i = 0; i < 4; i++)
            for (int j = 0; j < 4; j++)
                for (int r = 0; r < 4; r++)
                    acc[i][j][r] += cv[j];
    }

    // ---- el/er write (wave 0, C-layout col=mm -> n=2h+s); HEAD-MAJOR [h][NN] ----
    if (w == 0 && mm < 8) {
        float off = offlr[mm];
        int h = mm >> 1;
        float* dstp = (mm & 1) ? er : el;
        for (int i = 0; i < 4; i++)
            for (int r = 0; r < 4; r++) {
                int gr = rowbase + 16 * i + q * 4 + r;
                if (gr < NN) dstp[h * NN + gr] = accLR[i][r] + off;
            }
    }

    // ---- LDS-bounce feat16 store, SLICE-MAJOR layout ----
    for (int i = 0; i < 4; i++)
        for (int j = 0; j < 4; j++) {
            int gc = 64 * w + 16 * j + mm;
            for (int r = 0; r < 4; r++) {
                int rr = 16 * i + q * 4 + r;
                Alds[rr * AP + gc] = f2bf(acc[i][j][r]);
            }
        }
    __syncthreads();
    for (int it = 0; it < 8; it++) {
        int idx = it * 256 + tid;
        int rr = idx >> 5;
        int c16 = idx & 31;
        int gr = rowbase + rr;
        if (gr < NN) {
            int s = c16 >> 2, cc = c16 & 3;
            *(uint4*)(feat16 + ((size_t)s * NN + gr) * 32 + cc * 8) =
                *(const uint4*)(&Alds[rr * AP + c16 * 8]);
        }
    }
}

// ---------------- XCD-sharded softmax + aggregation ----------------
// Each block reads its hardware XCD id (HW_REG_XCC_ID, hwreg 20) and prefers
// the channel-slice s == xcc: its gathers then hit a contiguous 3.2 MB
// feat16 slice resident in its own L2. Work distribution via 8 per-slice
// atomic queues with steal-fallback (s0 loop) -- correct under ANY xcc values.
// Wave layout: half = l>>5 (2 dsts per wave), eo = (l>>2)&7 (8 edges in
// flight), ck = l&3 (8-ch chunk of the 32-ch slice). Reduce over eo via
// shfl_xor{4,8,16} AFTER the edge loop; 4 lanes per dst do the epilogue.
__launch_bounds__(256)
__global__ void k_aggx(const unsigned short* __restrict__ featS,
                       const float* __restrict__ el, const float* __restrict__ er,
                       const int* __restrict__ rowptr, const unsigned short* __restrict__ ssrc,
                       const unsigned short* __restrict__ residh, const float* __restrict__ residf,
                       const float* __restrict__ bnscale, const float* __restrict__ bnshift,
                       int use_bn, const float* __restrict__ bias, int act,
                       unsigned short* __restrict__ outh, float* __restrict__ poutf,
                       int final_mean, int* __restrict__ qcnt) {
    int xcc;
    asm volatile("s_getreg_b32 %0, hwreg(20, 0, 32)" : "=s"(xcc));
    xcc &= 7;
    const int l = threadIdx.x & 63;
    const int wave = threadIdx.x >> 6;
    const int half = l >> 5;
    const int r5 = l & 31;
    const int eo = r5 >> 2;
    const int ck = r5 & 3;
    __shared__ int sbase;

    for (int s0 = 0; s0 < 8; s0++) {
        int s = (xcc + s0) & 7;
        int h = s >> 1;
        const unsigned short* fs = featS + (size_t)s * NN * 32;
        const float* elh = el + (size_t)h * NN;
        const float* erh = er + (size_t)h * NN;
        int* qc = qcnt + s;
        while (true) {
            __syncthreads();
            if (threadIdx.x == 0) sbase = atomicAdd(qc, 64);
            __syncthreads();
            int base = sbase;
            if (base >= NN) break;
            int nb = base + 16 * wave;
            for (int t = 0; t < 8; t++) {
                int n = nb + 2 * t + half;
                int nc = (n < NN) ? n : (NN - 1);
                int beg = rowptr[nc], end = rowptr[nc + 1];
                float erv = erh[nc];
                float d = 0.f;
                float acc[8];
#pragma unroll
                for (int k = 0; k < 8; k++) acc[k] = 0.f;
                for (int e = beg; e < end; e += 8) {
                    int idx = e + eo;
                    int cidx = (idx < end) ? idx : beg;
                    int sw = ssrc[cidx];
                    float elv = elh[sw];
                    uint4 f = *(const uint4*)(fs + (size_t)sw * 32 + ck * 8);
                    float sc = elv + erv;
                    sc = (sc > 0.f) ? sc : SLOPE_A * sc;
                    float wg = (idx < end) ? __expf(sc) : 0.f;
                    d += wg;
                    acc[0] += bflo(f.x) * wg; acc[1] += bfhi(f.x) * wg;
                    acc[2] += bflo(f.y) * wg; acc[3] += bfhi(f.y) * wg;
                    acc[4] += bflo(f.z) * wg; acc[5] += bfhi(f.z) * wg;
                    acc[6] += bflo(f.w) * wg; acc[7] += bfhi(f.w) * wg;
                }
                // reduce over eo (lane bits 2..4), stays within each 32-lane half
                d += __shfl_xor(d, 4, 64);
                d += __shfl_xor(d, 8, 64);
                d += __shfl_xor(d, 16, 64);
#pragma unroll
                for (int k = 0; k < 8; k++) {
                    acc[k] += __shfl_xor(acc[k], 4, 64);
                    acc[k] += __shfl_xor(acc[k], 8, 64);
                    acc[k] += __shfl_xor(acc[k], 16, 64);
                }
                if (eo == 0 && n < NN) {
                    float invd = 1.f / fmaxf(d, 1e-9f);
                    int coff = s * 32 + ck * 8;
                    float v[8];
#pragma unroll
                    for (int k = 0; k < 8; k++) v[k] = acc[k] * invd;
                    float rr[8];
                    if (residf) {
                        float4 r0 = *(const float4*)(residf + (size_t)n * 256 + coff);
                        float4 r1 = *(const float4*)(residf + (size_t)n * 256 + coff + 4);
                        rr[0] = r0.x; rr[1] = r0.y; rr[2] = r0.z; rr[3] = r0.w;
                        rr[4] = r1.x; rr[5] = r1.y; rr[6] = r1.z; rr[7] = r1.w;
                    } else {
                        uint4 rv = *(const uint4*)(residh + (size_t)n * 256 + coff);
                        rr[0] = bflo(rv.x); rr[1] = bfhi(rv.x);
                        rr[2] = bflo(rv.y); rr[3] = bfhi(rv.y);
                        rr[4] = bflo(rv.z); rr[5] = bfhi(rv.z);
                        rr[6] = bflo(rv.w); rr[7] = bfhi(rv.w);
                    }
                    if (use_bn) {
                        float4 s0v = *(const float4*)(bnscale + coff);
                        float4 s1v = *(const float4*)(bnscale + coff + 4);
                        float4 h0v = *(const float4*)(bnshift + coff);
                        float4 h1v = *(const float4*)(bnshift + coff + 4);
                        rr[0] = rr[0] * s0v.x + h0v.x; rr[1] = rr[1] * s0v.y + h0v.y;
                        rr[2] = rr[2] * s0v.z + h0v.z; rr[3] = rr[3] * s0v.w + h0v.w;
                        rr[4] = rr[4] * s1v.x + h1v.x; rr[5] = rr[5] * s1v.y + h1v.y;
                        rr[6] = rr[6] * s1v.z + h1v.z; rr[7] = rr[7] * s1v.w + h1v.w;
                    }
                    float4 b0 = *(const float4*)(bias + coff);
                    float4 b1 = *(const float4*)(bias + coff + 4);
                    v[0] += rr[0] + b0.x; v[1] += rr[1] + b0.y;
                    v[2] += rr[2] + b0.z; v[3] += rr[3] + b0.w;
                    v[4] += rr[4] + b1.x; v[5] += rr[5] + b1.y;
                    v[6] += rr[6] + b1.z; v[7] += rr[7] + b1.w;
                    if (act) {
#pragma unroll
                        for (int k = 0; k < 8; k++)
                            v[k] = (v[k] > 0.f) ? v[k] : SLOPE_R * v[k];
                    }
                    if (!final_mean) {
                        uint4 o;
                        o.x = (unsigned)f2bf(v[0]) | ((unsigned)f2bf(v[1]) << 16);
                        o.y = (unsigned)f2bf(v[2]) | ((unsigned)f2bf(v[3]) << 16);
                        o.z = (unsigned)f2bf(v[4]) | ((unsigned)f2bf(v[5]) << 16);
                        o.w = (unsigned)f2bf(v[6]) | ((unsigned)f2bf(v[7]) << 16);
                        *(uint4*)(outh + (size_t)n * 256 + coff) = o;
                    } else {
                        float* pp = poutf + ((size_t)s * NN + n) * 32 + ck * 8;
                        *(float4*)pp = make_float4(v[0], v[1], v[2], v[3]);
                        *(float4*)(pp + 4) = make_float4(v[4], v[5], v[6], v[7]);
                    }
                }
            }
        }
    }
}

// ---------------- head-mean of the per-slice partials (final layer) ----------
// out[n][dd] = 0.25 * sum_h rst[n][h][dd]; channel h*64+dd lives in slice
// 2h + (dd>=32) at offset dd&31.
__global__ void k_mean(const float* __restrict__ pout, float* __restrict__ out) {
    int i = blockIdx.x * 256 + threadIdx.x;
    if (i >= NN * 16) return;
    int n = i >> 4;
    int c4 = (i & 15) * 4;          // dd base, multiple of 4
    int par = (c4 >= 32) ? 1 : 0;
    int cc = c4 & 31;
    float4 sum = make_float4(0.f, 0.f, 0.f, 0.f);
#pragma unroll
    for (int j = 0; j < 4; j++) {
        int s = 2 * j + par;
        float4 v = *(const float4*)(pout + ((size_t)s * NN + n) * 32 + cc);
        sum.x += v.x; sum.y += v.y; sum.z += v.z; sum.w += v.w;
    }
    sum.x *= 0.25f; sum.y *= 0.25f; sum.z *= 0.25f; sum.w *= 0.25f;
    *(float4*)(out + (size_t)n * 64 + c4) = sum;
}

// ---------------- BatchNorm stats: vectorized partials, no atomics (256 blocks) ----
__global__ void k_bnstats(const unsigned short* __restrict__ hh, float* __restrict__ pbuf) {
    __shared__ float ps[8 * 256];
    __shared__ float ps2[8 * 256];
    int t = threadIdx.x, b = blockIdx.x;
    int r8 = t >> 5, c32 = t & 31;
    int r0 = b * 196, r1 = min(r0 + 196, NN);
    float s[8], s2[8];
#pragma unroll
    for (int e = 0; e < 8; e++) { s[e] = 0.f; s2[e] = 0.f; }
    for (int r = r0 + r8; r < r1; r += 8) {
        uint4 v = *(const uint4*)(hh + (size_t)r * 256 + c32 * 8);
        const unsigned short* pv = (const unsigned short*)&v;
#pragma unroll
        for (int e = 0; e < 8; e++) {
            float f = bf2f(pv[e]);
            s[e] += f; s2[e] += f * f;
        }
    }
#pragma unroll
    for (int e = 0; e < 8; e++) {
        ps[r8 * 256 + c32 * 8 + e] = s[e];
        ps2[r8 * 256 + c32 * 8 + e] = s2[e];
    }
    __syncthreads();
    float ts = 0.f, ts2 = 0.f;
    for (int g = 0; g < 8; g++) { ts += ps[g * 256 + t]; ts2 += ps2[g * 256 + t]; }
    pbuf[b * 512 + t] = ts;
    pbuf[b * 512 + 256 + t] = ts2;
}

__global__ void k_bnfinal(const float* __restrict__ pbuf, const float* __restrict__ g,
                          const float* __restrict__ be, float* __restrict__ scale,
                          float* __restrict__ shift) {
    int t = threadIdx.x;
    float s = 0.f, s2 = 0.f;
    for (int b = 0; b < 256; b++) {
        s += pbuf[b * 512 + t];
        s2 += pbuf[b * 512 + 256 + t];
    }
    float mu = s * (1.f / NN);
    float var = s2 * (1.f / NN) - mu * mu;
    float rs = rsqrtf(var + 1e-5f);
    float sc = rs * g[t];
    scale[t] = sc;
    shift[t] = be[t] - mu * sc;
}

// ---------------- launcher ----------------
extern "C" void kernel_launch(void* const* d_in, const int* in_sizes, int n_in,
                              void* d_out, int out_size, void* d_ws, size_t ws_size,
                              hipStream_t stream) {
    const float* x   = (const float*)d_in[0];
    const int* src   = (const int*)d_in[1];
    const int* dst   = (const int*)d_in[2];
    const float* W1  = (const float*)d_in[3];
    const float* al1 = (const float*)d_in[4];
    const float* ar1 = (const float*)d_in[5];
    const float* b1  = (const float*)d_in[6];
    const float* W2  = (const float*)d_in[7];
    const float* al2 = (const float*)d_in[8];
    const float* ar2 = (const float*)d_in[9];
    const float* b2  = (const float*)d_in[10];
    const float* W3  = (const float*)d_in[11];
    const float* al3 = (const float*)d_in[12];
    const float* ar3 = (const float*)d_in[13];
    const float* b3  = (const float*)d_in[14];
    const float* g1  = (const float*)d_in[15];
    const float* be1 = (const float*)d_in[16];
    const float* g2  = (const float*)d_in[17];
    const float* be2 = (const float*)d_in[18];
    float* out = (float*)d_out;

    char* ws = (char*)d_ws;
    size_t off = 0;
    auto alloc = [&](size_t bytes) {
        void* p = ws + off;
        off += (bytes + 255) & ~(size_t)255;
        return p;
    };
    int* rowptr = (int*)alloc((NN + 1) * sizeof(int));
    int* cursor = (int*)alloc(NN * sizeof(int));
    int* cnt    = (int*)alloc(SCB * 256 * sizeof(int));
    int* loc    = (int*)alloc(SCB * 256 * sizeof(int));
    int* bsum   = (int*)alloc(SCB * sizeof(int));
    int* boff   = (int*)alloc(SCB * sizeof(int));
    int* qcnt   = (int*)alloc(24 * sizeof(int));
    unsigned short* ssrc = (unsigned short*)alloc(NE * sizeof(unsigned short));
    unsigned short* feat16 = (unsigned short*)alloc((size_t)NN * 256 * sizeof(unsigned short));
    unsigned short* hbuf   = (unsigned short*)alloc((size_t)NN * 256 * sizeof(unsigned short));
    float* el   = (float*)alloc((size_t)NN * 4 * sizeof(float));
    float* er   = (float*)alloc((size_t)NN * 4 * sizeof(float));
    float* pout = (float*)alloc((size_t)8 * NN * 32 * sizeof(float));
    unsigned short* Wfrag1  = (unsigned short*)alloc(65536 * sizeof(unsigned short));
    unsigned short* Wfrag2  = (unsigned short*)alloc(65536 * sizeof(unsigned short));
    unsigned short* wlrfrag = (unsigned short*)alloc(4096 * sizeof(unsigned short));
    float* offlr   = (float*)alloc(16 * sizeof(float));
    float* cvec    = (float*)alloc(256 * sizeof(float));
    float* pbuf    = (float*)alloc(256 * 512 * sizeof(float));
    float* bnscale = (float*)alloc(256 * sizeof(float));
    float* bnshift = (float*)alloc(256 * sizeof(float));

    // CSR build (graph identical for all layers)
    hipMemsetAsync(cnt, 0, NN * sizeof(int), stream);
    hipMemsetAsync(qcnt, 0, 24 * sizeof(int), stream);
    k_hist<<<(NE + 255) / 256, 256, 0, stream>>>(dst, cnt);
    k_scan1<<<SCB, 256, 0, stream>>>(cnt, loc, bsum);
    k_scan2<<<1, 256, 0, stream>>>(bsum, boff, rowptr);
    k_scan3<<<SCB, 256, 0, stream>>>(loc, boff, rowptr, cursor);
    k_scatter<<<(NE + 255) / 256, 256, 0, stream>>>(src, dst, cursor, ssrc);
    k_fold<<<40, 256, 0, stream>>>(W1, nullptr, nullptr, al1, ar1,
                                   Wfrag1, nullptr, wlrfrag, offlr, 0);

    const int GB = (NN + 63) / 64;  // 782
    const int XB = 2048;            // persistent-ish sharded agg grid

    // ---- layer 1 ----
    k_gemm<<<GB, 256, 0, stream>>>(x, 1, Wfrag1, nullptr, wlrfrag, offlr, feat16, el, er);
    k_aggx<<<XB, 256, 0, stream>>>(feat16, el, er, rowptr, ssrc, nullptr, x,
                                   nullptr, nullptr, 0, b1, 1, hbuf, nullptr, 0, qcnt);
    k_bnstats<<<256, 256, 0, stream>>>(hbuf, pbuf);
    k_bnfinal<<<1, 256, 0, stream>>>(pbuf, g1, be1, bnscale, bnshift);
    k_fold<<<296, 256, 0, stream>>>(W2, bnscale, bnshift, al2, ar2,
                                    Wfrag2, cvec, wlrfrag, offlr, 1);

    // ---- layer 2 ----
    k_gemm<<<GB, 256, 0, stream>>>(hbuf, 0, Wfrag2, cvec, wlrfrag, offlr, feat16, el, er);
    k_aggx<<<XB, 256, 0, stream>>>(feat16, el, er, rowptr, ssrc, hbuf, nullptr,
                                   bnscale, bnshift, 1, b2, 1, hbuf, nullptr, 0, qcnt + 8);
    k_bnstats<<<256, 256, 0, stream>>>(hbuf, pbuf);
    k_bnfinal<<<1, 256, 0, stream>>>(pbuf, g2, be2, bnscale, bnshift);
    k_fold<<<296, 256, 0, stream>>>(W3, bnscale, bnshift, al3, ar3,
                                    Wfrag2, cvec, wlrfrag, offlr, 1);

    // ---- layer 3 ----
    k_gemm<<<GB, 256, 0, stream>>>(hbuf, 0, Wfrag2, cvec, wlrfrag, offlr, feat16, el, er);
    k_aggx<<<XB, 256, 0, stream>>>(feat16, el, er, rowptr, ssrc, hbuf, nullptr,
                                   bnscale, bnshift, 1, b3, 0, nullptr, pout, 1, qcnt + 16);
    k_mean<<<(NN * 16 + 255) / 256, 256, 0, stream>>>(pout, out);
}

// Round 7
// 1174.926 us; speedup vs baseline: 1.1408x; 1.1408x over previous
//
#include <hip/hip_runtime.h>

constexpr int NN = 50000;     // nodes
constexpr int NE = 800000;    // edges
constexpr float SLOPE_A = 0.2f;   // attention leaky_relu
constexpr float SLOPE_R = 0.01f;  // activation leaky_relu
constexpr int SCB = 196;      // scan blocks: 196*256 = 50176 >= NN

typedef __attribute__((ext_vector_type(8))) short bf16x8;
typedef __attribute__((ext_vector_type(4))) float f32x4;

__device__ __forceinline__ unsigned short f2bf(float f) {
    union { float f; unsigned u; } v; v.f = f;
    unsigned u = v.u;
    unsigned r = u + 0x7fffu + ((u >> 16) & 1u);  // round-to-nearest-even
    return (unsigned short)(r >> 16);
}
__device__ __forceinline__ float bf2f(unsigned short s) {
    union { unsigned u; float f; } v; v.u = ((unsigned)s) << 16;
    return v.f;
}
// low/high bf16 halves of a packed u32 -> f32 (1 VALU op each)
__device__ __forceinline__ float bflo(unsigned u) {
    union { unsigned u; float f; } v; v.u = u << 16; return v.f;
}
__device__ __forceinline__ float bfhi(unsigned u) {
    union { unsigned u; float f; } v; v.u = u & 0xffff0000u; return v.f;
}

// ---------------- CSR build ----------------
__global__ void k_hist(const int* __restrict__ dst, int* __restrict__ cnt) {
    int i = blockIdx.x * 256 + threadIdx.x;
    if (i < NE) atomicAdd(&cnt[dst[i]], 1);
}

__global__ void k_scan1(const int* __restrict__ cnt, int* __restrict__ loc,
                        int* __restrict__ bsum) {
    __shared__ int sh[256];
    int t = threadIdx.x;
    int i = blockIdx.x * 256 + t;
    int v = (i < NN) ? cnt[i] : 0;
    sh[t] = v;
    __syncthreads();
    for (int off = 1; off < 256; off <<= 1) {
        int tmp = (t >= off) ? sh[t - off] : 0;
        __syncthreads();
        sh[t] += tmp;
        __syncthreads();
    }
    loc[i] = sh[t] - v;
    if (t == 255) bsum[blockIdx.x] = sh[255];
}

__global__ void k_scan2(const int* __restrict__ bsum, int* __restrict__ boff,
                        int* __restrict__ rowptr) {
    __shared__ int sh[256];
    int t = threadIdx.x;
    int v = (t < SCB) ? bsum[t] : 0;
    sh[t] = v;
    __syncthreads();
    for (int off = 1; off < 256; off <<= 1) {
        int tmp = (t >= off) ? sh[t - off] : 0;
        __syncthreads();
        sh[t] += tmp;
        __syncthreads();
    }
    if (t < SCB) boff[t] = sh[t] - v;
    if (t == 255) rowptr[NN] = sh[255];
}

__global__ void k_scan3(const int* __restrict__ loc, const int* __restrict__ boff,
                        int* __restrict__ rowptr, int* __restrict__ cursor) {
    int i = blockIdx.x * 256 + threadIdx.x;
    if (i < NN) {
        int r = loc[i] + boff[blockIdx.x];
        rowptr[i] = r;
        cursor[i] = r;
    }
}

// src ids fit in 16 bits (NN < 65536)
__global__ void k_scatter(const int* __restrict__ src, const int* __restrict__ dst,
                          int* __restrict__ cursor, unsigned short* __restrict__ ssrc) {
    int i = blockIdx.x * 256 + threadIdx.x;
    if (i < NE) {
        int d = dst[i];
        int pos = atomicAdd(&cursor[d], 1);
        ssrc[pos] = (unsigned short)src[i];
    }
}

// ---------------- fold: Wfrag + cvec + wl/wr fragment + offlr, all from fp32 W ----
__global__ void k_fold(const float* __restrict__ W, const float* __restrict__ sc,
                       const float* __restrict__ sh, const float* __restrict__ al,
                       const float* __restrict__ ar, unsigned short* __restrict__ Wfrag,
                       float* __restrict__ cvec, unsigned short* __restrict__ wlrfrag,
                       float* __restrict__ offlr, int has_bn) {
    int b = blockIdx.x;
    if (b < 32) {
        int gid = b * 256 + threadIdx.x;   // < 8192; one thread = 8 shorts
        int lane = gid & 63;
        int frag = gid >> 6;               // 0..127
        int j = frag & 3, kc = (frag >> 2) & 7, w = frag >> 5;
        int mm = lane & 15, q = lane >> 4;
        int n = 64 * w + 16 * j + mm;
        int k0 = kc * 32 + q * 8;
        unsigned short o[8];
#pragma unroll
        for (int t = 0; t < 8; t++) {
            float wv = W[(size_t)(k0 + t) * 256 + n];
            if (sc) wv *= sc[k0 + t];
            o[t] = f2bf(wv);
        }
        *(uint4*)(Wfrag + (size_t)gid * 8) = *(const uint4*)o;
    } else if (has_bn && b < 288) {
        __shared__ float red[256];
        int n = b - 32, k = threadIdx.x;
        red[k] = sh[k] * W[(size_t)k * 256 + n];
        __syncthreads();
        for (int off = 128; off > 0; off >>= 1) {
            if (k < off) red[k] += red[k + off];
            __syncthreads();
        }
        if (k == 0) cvec[n] = red[0];
    } else {
        int n = b - (has_bn ? 288 : 32);   // 0..7
        int h = n >> 1;
        const float* a = (n & 1) ? ar : al;
        int k = threadIdx.x;
        float raw = 0.f;
#pragma unroll 8
        for (int d = 0; d < 64; d++)
            raw += W[(size_t)k * 256 + 64 * h + d] * a[h * 64 + d];
        float val = (sc ? sc[k] : 1.f) * raw;
        int kc = k >> 5, rem = k & 31, q = rem >> 3, t = rem & 7;  // k = kc*32+q*8+t
        wlrfrag[kc * 512 + (q * 16 + n) * 8 + t] = f2bf(val);
        wlrfrag[kc * 512 + (q * 16 + n + 8) * 8 + t] = 0;   // zero the unused col
        __shared__ float red[256];
        red[k] = sh ? sh[k] * raw : 0.f;
        __syncthreads();
        for (int off = 128; off > 0; off >>= 1) {
            if (k < off) red[k] += red[k + off];
            __syncthreads();
        }
        if (k == 0) offlr[n] = red[0];
    }
}

// ---------------- GEMM: feat = A @ Wfrag (+cvec); el/er via extra MFMA --------
// feat16 (and hbuf) are SLICE-MAJOR [slice=ch/32][node][32ch]; el/er head-major.
// af32==0 input (hbuf) is slice-major; af32==1 input (x) is row-major f32.
__launch_bounds__(256)
__global__ void k_gemm(const void* __restrict__ Araw, int af32,
                       const unsigned short* __restrict__ Wfrag,
                       const float* __restrict__ cvec,
                       const unsigned short* __restrict__ wlrfrag,
                       const float* __restrict__ offlr,
                       unsigned short* __restrict__ feat16, float* __restrict__ el,
                       float* __restrict__ er) {
    constexpr int AP = 264;  // A lds pitch in bf16 elems (row start 16B-aligned)
    __shared__ __align__(16) unsigned short Alds[64 * AP];
    const int tid = threadIdx.x;
    const int rowbase = blockIdx.x * 64;

    // stage A: 64 rows x 256 bf16
    if (af32) {
        const float* A = (const float*)Araw;
        int r = tid >> 6;
        int c4 = tid & 63;
        for (int it = 0; it < 16; it++) {
            int rr = it * 4 + r;
            int gr = rowbase + rr;
            float4 v = make_float4(0.f, 0.f, 0.f, 0.f);
            if (gr < NN) v = *(const float4*)(A + (size_t)gr * 256 + c4 * 4);
            ushort4 pv;
            pv.x = f2bf(v.x); pv.y = f2bf(v.y); pv.z = f2bf(v.z); pv.w = f2bf(v.w);
            *(ushort4*)(&Alds[rr * AP + c4 * 4]) = pv;
        }
    } else {
        const unsigned short* A = (const unsigned short*)Araw;
        for (int it = 0; it < 8; it++) {
            int idx = it * 256 + tid;
            int rr = idx >> 5;
            int c16 = idx & 31;
            int gr = rowbase + rr;
            uint4 v = make_uint4(0u, 0u, 0u, 0u);
            if (gr < NN)
                v = *(const uint4*)(A + ((size_t)(c16 >> 2) * NN + gr) * 32 + (c16 & 3) * 8);
            *(uint4*)(&Alds[rr * AP + c16 * 8]) = v;
        }
    }
    __syncthreads();

    f32x4 acc[4][4];
    for (int i = 0; i < 4; i++)
        for (int j = 0; j < 4; j++)
            acc[i][j] = (f32x4){0.f, 0.f, 0.f, 0.f};
    f32x4 accLR[4];
    for (int i = 0; i < 4; i++) accLR[i] = (f32x4){0.f, 0.f, 0.f, 0.f};

    const int lane = tid & 63, w = tid >> 6;
    const int mm = lane & 15, q = lane >> 4;

    const unsigned short* bbase = Wfrag + ((size_t)w * 8 * 4) * 512 + (size_t)lane * 8;

#pragma unroll
    for (int kc = 0; kc < 8; kc++) {
        bf16x8 a[4], b[4];
        for (int i = 0; i < 4; i++)
            a[i] = *(const bf16x8*)(&Alds[(16 * i + mm) * AP + kc * 32 + q * 8]);
        for (int j = 0; j < 4; j++)
            b[j] = *(const bf16x8*)(bbase + (size_t)(kc * 4 + j) * 512);
        for (int i = 0; i < 4; i++)
            for (int j = 0; j < 4; j++)
                acc[i][j] = __builtin_amdgcn_mfma_f32_16x16x32_bf16(a[i], b[j], acc[i][j], 0, 0, 0);
        if (w == 0) {
            bf16x8 blr = *(const bf16x8*)(wlrfrag + kc * 512 + lane * 8);
            for (int i = 0; i < 4; i++)
                accLR[i] = __builtin_amdgcn_mfma_f32_16x16x32_bf16(a[i], blr, accLR[i], 0, 0, 0);
        }
    }
    __syncthreads();   // all waves done reading Alds before epilogue reuses it

    // ---- folded-BN column offset on feat ----
    if (cvec) {
        float cv[4];
        for (int j = 0; j < 4; j++) cv[j] = cvec[64 * w + 16 * j + mm];
        for (int i = 0; i < 4; i++)
            for (int j = 0; j < 4; j++)
                for (int r = 0; r < 4; r++)
                    acc[i][j][r] += cv[j];
    }

    // ---- el/er write (wave 0, C-layout col=mm -> n=2h+s); HEAD-MAJOR [h][NN] ----
    if (w == 0 && mm < 8) {
        float off = offlr[mm];
        int h = mm >> 1;
        float* dstp = (mm & 1) ? er : el;
        for (int i = 0; i < 4; i++)
            for (int r = 0; r < 4; r++) {
                int gr = rowbase + 16 * i + q * 4 + r;
                if (gr < NN) dstp[h * NN + gr] = accLR[i][r] + off;
            }
    }

    // ---- LDS-bounce feat16 store, SLICE-MAJOR layout ----
    for (int i = 0; i < 4; i++)
        for (int j = 0; j < 4; j++) {
            int gc = 64 * w + 16 * j + mm;
            for (int r = 0; r < 4; r++) {
                int rr = 16 * i + q * 4 + r;
                Alds[rr * AP + gc] = f2bf(acc[i][j][r]);
            }
        }
    __syncthreads();
    for (int it = 0; it < 8; it++) {
        int idx = it * 256 + tid;
        int rr = idx >> 5;
        int c16 = idx & 31;
        int gr = rowbase + rr;
        if (gr < NN) {
            int s = c16 >> 2, cc = c16 & 3;
            *(uint4*)(feat16 + ((size_t)s * NN + gr) * 32 + cc * 8) =
                *(const uint4*)(&Alds[rr * AP + c16 * 8]);
        }
    }
}

// ---------------- XCD-sharded softmax + aggregation, R5-grade MLP ----------------
// Block prefers slice s == HW XCC id (per-slice atomic queues, steal fallback:
// correct under ANY xcc values; monotone-counter volatile pre-check makes
// drained-queue probes cheap). 16-lane group per dst (4 dsts/wave):
//   eo=(l>>2)&3 edge class, ck=l&3 16B chunk of the 64B slice row.
// Edge loop step 16 with 4-deep unroll: 4 independent direct-addressed 16B
// feat gathers in flight per lane (R5's proven depth), zero cross-lane ops in
// the loop. Reduce over eo via shfl_xor{4,8} after the loop.
// outh/resid are slice-major -> full-sector 256B/wave writes, slice-local reads.
__launch_bounds__(256)
__global__ void k_aggx(const unsigned short* __restrict__ featS,
                       const float* __restrict__ el, const float* __restrict__ er,
                       const int* __restrict__ rowptr, const unsigned short* __restrict__ ssrc,
                       const unsigned short* __restrict__ residh, const float* __restrict__ residf,
                       const float* __restrict__ bnscale, const float* __restrict__ bnshift,
                       int use_bn, const float* __restrict__ bias, int act,
                       unsigned short* __restrict__ outh, float* __restrict__ poutf,
                       int final_mean, int* __restrict__ qcnt) {
    int xcc;
    asm volatile("s_getreg_b32 %0, hwreg(20, 0, 32)" : "=s"(xcc));
    xcc &= 7;
    const int l = threadIdx.x & 63;
    const int g = l >> 4;           // dst group within wave
    const int eo = (l >> 2) & 3;    // edge class
    const int ck = l & 3;           // 16B chunk of 64B slice row

    for (int s0 = 0; s0 < 8; s0++) {
        int s = (xcc + s0) & 7;
        int h = s >> 1;
        const unsigned short* fs = featS + (size_t)s * NN * 32;
        const unsigned short* rs = residh ? residh + (size_t)s * NN * 32 : (const unsigned short*)0;
        const float* elh = el + (size_t)h * NN;
        const float* erh = er + (size_t)h * NN;
        const int coff = s * 32 + ck * 8;
        int* qc = qcnt + s * 16;
        volatile int* qv = (volatile int*)qc;
        while (true) {
            if (*qv >= NN) break;          // monotone counter: stale-low is safe
            int base = 0;
            if (l == 0) base = atomicAdd(qc, 32);
            base = __shfl(base, 0, 64);
            if (base >= NN) break;
            for (int t = 0; t < 8; t++) {
                int n = base + 4 * t + g;
                int nc = (n < NN) ? n : (NN - 1);
                int beg = rowptr[nc], end = rowptr[nc + 1];
                float erv = erh[nc];
                float d = 0.f;
                float acc[8];
#pragma unroll
                for (int k = 0; k < 8; k++) acc[k] = 0.f;
                for (int e = beg; e < end; e += 16) {
                    int ss[4];
#pragma unroll
                    for (int u = 0; u < 4; u++) {
                        int idx = e + 4 * u + eo;
                        ss[u] = ssrc[(idx < end) ? idx : beg];
                    }
                    float aa[4];
#pragma unroll
                    for (int u = 0; u < 4; u++) aa[u] = elh[ss[u]];
                    uint4 ff[4];
#pragma unroll
                    for (int u = 0; u < 4; u++)
                        ff[u] = *(const uint4*)(fs + (size_t)ss[u] * 32 + ck * 8);
#pragma unroll
                    for (int u = 0; u < 4; u++) {
                        float sc = aa[u] + erv;
                        sc = (sc > 0.f) ? sc : SLOPE_A * sc;
                        float wg = ((e + 4 * u + eo) < end) ? __expf(sc) : 0.f;
                        d += wg;
                        acc[0] += bflo(ff[u].x) * wg; acc[1] += bfhi(ff[u].x) * wg;
                        acc[2] += bflo(ff[u].y) * wg; acc[3] += bfhi(ff[u].y) * wg;
                        acc[4] += bflo(ff[u].z) * wg; acc[5] += bfhi(ff[u].z) * wg;
                        acc[6] += bflo(ff[u].w) * wg; acc[7] += bfhi(ff[u].w) * wg;
                    }
                }
                // reduce over eo (lane bits 2,3) within each 16-lane group
                d += __shfl_xor(d, 4, 64);
                d += __shfl_xor(d, 8, 64);
#pragma unroll
                for (int k = 0; k < 8; k++) {
                    acc[k] += __shfl_xor(acc[k], 4, 64);
                    acc[k] += __shfl_xor(acc[k], 8, 64);
                }
                if (eo == 0 && n < NN) {
                    float invd = 1.f / fmaxf(d, 1e-9f);
                    float v[8];
#pragma unroll
                    for (int k = 0; k < 8; k++) v[k] = acc[k] * invd;
                    float rr[8];
                    if (residf) {
                        float4 r0 = *(const float4*)(residf + (size_t)n * 256 + coff);
                        float4 r1 = *(const float4*)(residf + (size_t)n * 256 + coff + 4);
                        rr[0] = r0.x; rr[1] = r0.y; rr[2] = r0.z; rr[3] = r0.w;
                        rr[4] = r1.x; rr[5] = r1.y; rr[6] = r1.z; rr[7] = r1.w;
                    } else {
                        uint4 rv = *(const uint4*)(rs + (size_t)n * 32 + ck * 8);
                        rr[0] = bflo(rv.x); rr[1] = bfhi(rv.x);
                        rr[2] = bflo(rv.y); rr[3] = bfhi(rv.y);
                        rr[4] = bflo(rv.z); rr[5] = bfhi(rv.z);
                        rr[6] = bflo(rv.w); rr[7] = bfhi(rv.w);
                    }
                    if (use_bn) {
                        float4 s0v = *(const float4*)(bnscale + coff);
                        float4 s1v = *(const float4*)(bnscale + coff + 4);
                        float4 h0v = *(const float4*)(bnshift + coff);
                        float4 h1v = *(const float4*)(bnshift + coff + 4);
                        rr[0] = rr[0] * s0v.x + h0v.x; rr[1] = rr[1] * s0v.y + h0v.y;
                        rr[2] = rr[2] * s0v.z + h0v.z; rr[3] = rr[3] * s0v.w + h0v.w;
                        rr[4] = rr[4] * s1v.x + h1v.x; rr[5] = rr[5] * s1v.y + h1v.y;
                        rr[6] = rr[6] * s1v.z + h1v.z; rr[7] = rr[7] * s1v.w + h1v.w;
                    }
                    float4 b0 = *(const float4*)(bias + coff);
                    float4 b1 = *(const float4*)(bias + coff + 4);
                    v[0] += rr[0] + b0.x; v[1] += rr[1] + b0.y;
                    v[2] += rr[2] + b0.z; v[3] += rr[3] + b0.w;
                    v[4] += rr[4] + b1.x; v[5] += rr[5] + b1.y;
                    v[6] += rr[6] + b1.z; v[7] += rr[7] + b1.w;
                    if (act) {
#pragma unroll
                        for (int k = 0; k < 8; k++)
                            v[k] = (v[k] > 0.f) ? v[k] : SLOPE_R * v[k];
                    }
                    if (!final_mean) {
                        uint4 o;
                        o.x = (unsigned)f2bf(v[0]) | ((unsigned)f2bf(v[1]) << 16);
                        o.y = (unsigned)f2bf(v[2]) | ((unsigned)f2bf(v[3]) << 16);
                        o.z = (unsigned)f2bf(v[4]) | ((unsigned)f2bf(v[5]) << 16);
                        o.w = (unsigned)f2bf(v[6]) | ((unsigned)f2bf(v[7]) << 16);
                        *(uint4*)(outh + ((size_t)s * NN + n) * 32 + ck * 8) = o;
                    } else {
                        float* pp = poutf + ((size_t)s * NN + n) * 32 + ck * 8;
                        *(float4*)pp = make_float4(v[0], v[1], v[2], v[3]);
                        *(float4*)(pp + 4) = make_float4(v[4], v[5], v[6], v[7]);
                    }
                }
            }
        }
    }
}

// ---------------- head-mean of the per-slice partials (final layer) ----------
__global__ void k_mean(const float* __restrict__ pout, float* __restrict__ out) {
    int i = blockIdx.x * 256 + threadIdx.x;
    if (i >= NN * 16) return;
    int n = i >> 4;
    int c4 = (i & 15) * 4;          // dd base, multiple of 4
    int par = (c4 >= 32) ? 1 : 0;
    int cc = c4 & 31;
    float4 sum = make_float4(0.f, 0.f, 0.f, 0.f);
#pragma unroll
    for (int j = 0; j < 4; j++) {
        int s = 2 * j + par;
        float4 v = *(const float4*)(pout + ((size_t)s * NN + n) * 32 + cc);
        sum.x += v.x; sum.y += v.y; sum.z += v.z; sum.w += v.w;
    }
    sum.x *= 0.25f; sum.y *= 0.25f; sum.z *= 0.25f; sum.w *= 0.25f;
    *(float4*)(out + (size_t)n * 64 + c4) = sum;
}

// ---------------- BatchNorm stats over slice-major hbuf ----------------
__global__ void k_bnstats(const unsigned short* __restrict__ hh, float* __restrict__ pbuf) {
    __shared__ float ps[8 * 256];
    __shared__ float ps2[8 * 256];
    int t = threadIdx.x, b = blockIdx.x;
    int r8 = t >> 5, c32 = t & 31;
    int sl = c32 >> 2, cc = (c32 & 3) * 8;
    int r0 = b * 196, r1 = min(r0 + 196, NN);
    float s[8], s2[8];
#pragma unroll
    for (int e = 0; e < 8; e++) { s[e] = 0.f; s2[e] = 0.f; }
    for (int r = r0 + r8; r < r1; r += 8) {
        uint4 v = *(const uint4*)(hh + ((size_t)sl * NN + r) * 32 + cc);
        const unsigned short* pv = (const unsigned short*)&v;
#pragma unroll
        for (int e = 0; e < 8; e++) {
            float f = bf2f(pv[e]);
            s[e] += f; s2[e] += f * f;
        }
    }
#pragma unroll
    for (int e = 0; e < 8; e++) {
        ps[r8 * 256 + c32 * 8 + e] = s[e];
        ps2[r8 * 256 + c32 * 8 + e] = s2[e];
    }
    __syncthreads();
    float ts = 0.f, ts2 = 0.f;
    for (int g = 0; g < 8; g++) { ts += ps[g * 256 + t]; ts2 += ps2[g * 256 + t]; }
    pbuf[b * 512 + t] = ts;
    pbuf[b * 512 + 256 + t] = ts2;
}

__global__ void k_bnfinal(const float* __restrict__ pbuf, const float* __restrict__ g,
                          const float* __restrict__ be, float* __restrict__ scale,
                          float* __restrict__ shift) {
    int t = threadIdx.x;
    float s = 0.f, s2 = 0.f;
    for (int b = 0; b < 256; b++) {
        s += pbuf[b * 512 + t];
        s2 += pbuf[b * 512 + 256 + t];
    }
    float mu = s * (1.f / NN);
    float var = s2 * (1.f / NN) - mu * mu;
    float rs = rsqrtf(var + 1e-5f);
    float sc = rs * g[t];
    scale[t] = sc;
    shift[t] = be[t] - mu * sc;
}

// ---------------- launcher ----------------
extern "C" void kernel_launch(void* const* d_in, const int* in_sizes, int n_in,
                              void* d_out, int out_size, void* d_ws, size_t ws_size,
                              hipStream_t stream) {
    const float* x   = (const float*)d_in[0];
    const int* src   = (const int*)d_in[1];
    const int* dst   = (const int*)d_in[2];
    const float* W1  = (const float*)d_in[3];
    const float* al1 = (const float*)d_in[4];
    const float* ar1 = (const float*)d_in[5];
    const float* b1  = (const float*)d_in[6];
    const float* W2  = (const float*)d_in[7];
    const float* al2 = (const float*)d_in[8];
    const float* ar2 = (const float*)d_in[9];
    const float* b2  = (const float*)d_in[10];
    const float* W3  = (const float*)d_in[11];
    const float* al3 = (const float*)d_in[12];
    const float* ar3 = (const float*)d_in[13];
    const float* b3  = (const float*)d_in[14];
    const float* g1  = (const float*)d_in[15];
    const float* be1 = (const float*)d_in[16];
    const float* g2  = (const float*)d_in[17];
    const float* be2 = (const float*)d_in[18];
    float* out = (float*)d_out;

    char* ws = (char*)d_ws;
    size_t off = 0;
    auto alloc = [&](size_t bytes) {
        void* p = ws + off;
        off += (bytes + 255) & ~(size_t)255;
        return p;
    };
    int* rowptr = (int*)alloc((NN + 1) * sizeof(int));
    int* cursor = (int*)alloc(NN * sizeof(int));
    int* cnt    = (int*)alloc(SCB * 256 * sizeof(int));
    int* loc    = (int*)alloc(SCB * 256 * sizeof(int));
    int* bsum   = (int*)alloc(SCB * sizeof(int));
    int* boff   = (int*)alloc(SCB * sizeof(int));
    int* qcnt   = (int*)alloc(3 * 8 * 16 * sizeof(int));   // 64B-strided counters
    unsigned short* ssrc = (unsigned short*)alloc(NE * sizeof(unsigned short));
    unsigned short* feat16 = (unsigned short*)alloc((size_t)NN * 256 * sizeof(unsigned short));
    unsigned short* hbuf   = (unsigned short*)alloc((size_t)NN * 256 * sizeof(unsigned short));
    float* el   = (float*)alloc((size_t)NN * 4 * sizeof(float));
    float* er   = (float*)alloc((size_t)NN * 4 * sizeof(float));
    float* pout = (float*)alloc((size_t)8 * NN * 32 * sizeof(float));
    unsigned short* Wfrag1  = (unsigned short*)alloc(65536 * sizeof(unsigned short));
    unsigned short* Wfrag2  = (unsigned short*)alloc(65536 * sizeof(unsigned short));
    unsigned short* wlrfrag = (unsigned short*)alloc(4096 * sizeof(unsigned short));
    float* offlr   = (float*)alloc(16 * sizeof(float));
    float* cvec    = (float*)alloc(256 * sizeof(float));
    float* pbuf    = (float*)alloc(256 * 512 * sizeof(float));
    float* bnscale = (float*)alloc(256 * sizeof(float));
    float* bnshift = (float*)alloc(256 * sizeof(float));

    // CSR build (graph identical for all layers)
    hipMemsetAsync(cnt, 0, NN * sizeof(int), stream);
    hipMemsetAsync(qcnt, 0, 3 * 8 * 16 * sizeof(int), stream);
    k_hist<<<(NE + 255) / 256, 256, 0, stream>>>(dst, cnt);
    k_scan1<<<SCB, 256, 0, stream>>>(cnt, loc, bsum);
    k_scan2<<<1, 256, 0, stream>>>(bsum, boff, rowptr);
    k_scan3<<<SCB, 256, 0, stream>>>(loc, boff, rowptr, cursor);
    k_scatter<<<(NE + 255) / 256, 256, 0, stream>>>(src, dst, cursor, ssrc);
    k_fold<<<40, 256, 0, stream>>>(W1, nullptr, nullptr, al1, ar1,
                                   Wfrag1, nullptr, wlrfrag, offlr, 0);

    const int GB = (NN + 63) / 64;  // 782
    const int XB = 2048;

    // ---- layer 1 ----
    k_gemm<<<GB, 256, 0, stream>>>(x, 1, Wfrag1, nullptr, wlrfrag, offlr, feat16, el, er);
    k_aggx<<<XB, 256, 0, stream>>>(feat16, el, er, rowptr, ssrc, nullptr, x,
                                   nullptr, nullptr, 0, b1, 1, hbuf, nullptr, 0, qcnt);
    k_bnstats<<<256, 256, 0, stream>>>(hbuf, pbuf);
    k_bnfinal<<<1, 256, 0, stream>>>(pbuf, g1, be1, bnscale, bnshift);
    k_fold<<<296, 256, 0, stream>>>(W2, bnscale, bnshift, al2, ar2,
                                    Wfrag2, cvec, wlrfrag, offlr, 1);

    // ---- layer 2 ----
    k_gemm<<<GB, 256, 0, stream>>>(hbuf, 0, Wfrag2, cvec, wlrfrag, offlr, feat16, el, er);
    k_aggx<<<XB, 256, 0, stream>>>(feat16, el, er, rowptr, ssrc, hbuf, nullptr,
                                   bnscale, bnshift, 1, b2, 1, hbuf, nullptr, 0, qcnt + 128);
    k_bnstats<<<256, 256, 0, stream>>>(hbuf, pbuf);
    k_bnfinal<<<1, 256, 0, stream>>>(pbuf, g2, be2, bnscale, bnshift);
    k_fold<<<296, 256, 0, stream>>>(W3, bnscale, bnshift, al3, ar3,
                                    Wfrag2, cvec, wlrfrag, offlr, 1);

    // ---- layer 3 ----
    k_gemm<<<GB, 256, 0, stream>>>(hbuf, 0, Wfrag2, cvec, wlrfrag, offlr, feat16, el, er);
    k_aggx<<<XB, 256, 0, stream>>>(feat16, el, er, rowptr, ssrc, hbuf, nullptr,
                                   bnscale, bnshift, 1, b3, 0, nullptr, pout, 1, qcnt + 256);
    k_mean<<<(NN * 16 + 255) / 256, 256, 0, stream>>>(pout, out);
}

// Round 8
// 1052.774 us; speedup vs baseline: 1.2732x; 1.1160x over previous
//
#include <hip/hip_runtime.h>

constexpr int NN = 50000;     // nodes
constexpr int NE = 800000;    // edges
constexpr float SLOPE_A = 0.2f;   // attention leaky_relu
constexpr float SLOPE_R = 0.01f;  // activation leaky_relu
constexpr int SCB = 196;      // scan blocks: 196*256 = 50176 >= NN
constexpr int SUBN = 6250;    // nodes per sub-queue (50000 / 8)

typedef __attribute__((ext_vector_type(8))) short bf16x8;
typedef __attribute__((ext_vector_type(4))) float f32x4;

__device__ __forceinline__ unsigned short f2bf(float f) {
    union { float f; unsigned u; } v; v.f = f;
    unsigned u = v.u;
    unsigned r = u + 0x7fffu + ((u >> 16) & 1u);  // round-to-nearest-even
    return (unsigned short)(r >> 16);
}
__device__ __forceinline__ float bf2f(unsigned short s) {
    union { unsigned u; float f; } v; v.u = ((unsigned)s) << 16;
    return v.f;
}
// low/high bf16 halves of a packed u32 -> f32 (1 VALU op each)
__device__ __forceinline__ float bflo(unsigned u) {
    union { unsigned u; float f; } v; v.u = u << 16; return v.f;
}
__device__ __forceinline__ float bfhi(unsigned u) {
    union { unsigned u; float f; } v; v.u = u & 0xffff0000u; return v.f;
}

// ---------------- CSR build ----------------
__global__ void k_hist(const int* __restrict__ dst, int* __restrict__ cnt) {
    int i = blockIdx.x * 256 + threadIdx.x;
    if (i < NE) atomicAdd(&cnt[dst[i]], 1);
}

__global__ void k_scan1(const int* __restrict__ cnt, int* __restrict__ loc,
                        int* __restrict__ bsum) {
    __shared__ int sh[256];
    int t = threadIdx.x;
    int i = blockIdx.x * 256 + t;
    int v = (i < NN) ? cnt[i] : 0;
    sh[t] = v;
    __syncthreads();
    for (int off = 1; off < 256; off <<= 1) {
        int tmp = (t >= off) ? sh[t - off] : 0;
        __syncthreads();
        sh[t] += tmp;
        __syncthreads();
    }
    loc[i] = sh[t] - v;
    if (t == 255) bsum[blockIdx.x] = sh[255];
}

__global__ void k_scan2(const int* __restrict__ bsum, int* __restrict__ boff,
                        int* __restrict__ rowptr) {
    __shared__ int sh[256];
    int t = threadIdx.x;
    int v = (t < SCB) ? bsum[t] : 0;
    sh[t] = v;
    __syncthreads();
    for (int off = 1; off < 256; off <<= 1) {
        int tmp = (t >= off) ? sh[t - off] : 0;
        __syncthreads();
        sh[t] += tmp;
        __syncthreads();
    }
    if (t < SCB) boff[t] = sh[t] - v;
    if (t == 255) rowptr[NN] = sh[255];
}

__global__ void k_scan3(const int* __restrict__ loc, const int* __restrict__ boff,
                        int* __restrict__ rowptr, int* __restrict__ cursor) {
    int i = blockIdx.x * 256 + threadIdx.x;
    if (i < NN) {
        int r = loc[i] + boff[blockIdx.x];
        rowptr[i] = r;
        cursor[i] = r;
    }
}

// src/dst ids fit in 16 bits (NN < 65536)
__global__ void k_scatter(const int* __restrict__ src, const int* __restrict__ dst,
                          int* __restrict__ cursor, unsigned short* __restrict__ ssrc,
                          unsigned short* __restrict__ sdst) {
    int i = blockIdx.x * 256 + threadIdx.x;
    if (i < NE) {
        int d = dst[i];
        int pos = atomicAdd(&cursor[d], 1);
        ssrc[pos] = (unsigned short)src[i];
        sdst[pos] = (unsigned short)d;
    }
}

// ---------------- fold: Wfrag + cvec + wl/wr fragment + offlr, all from fp32 W ----
__global__ void k_fold(const float* __restrict__ W, const float* __restrict__ sc,
                       const float* __restrict__ sh, const float* __restrict__ al,
                       const float* __restrict__ ar, unsigned short* __restrict__ Wfrag,
                       float* __restrict__ cvec, unsigned short* __restrict__ wlrfrag,
                       float* __restrict__ offlr, int has_bn) {
    int b = blockIdx.x;
    if (b < 32) {
        int gid = b * 256 + threadIdx.x;   // < 8192; one thread = 8 shorts
        int lane = gid & 63;
        int frag = gid >> 6;               // 0..127
        int j = frag & 3, kc = (frag >> 2) & 7, w = frag >> 5;
        int mm = lane & 15, q = lane >> 4;
        int n = 64 * w + 16 * j + mm;
        int k0 = kc * 32 + q * 8;
        unsigned short o[8];
#pragma unroll
        for (int t = 0; t < 8; t++) {
            float wv = W[(size_t)(k0 + t) * 256 + n];
            if (sc) wv *= sc[k0 + t];
            o[t] = f2bf(wv);
        }
        *(uint4*)(Wfrag + (size_t)gid * 8) = *(const uint4*)o;
    } else if (has_bn && b < 288) {
        __shared__ float red[256];
        int n = b - 32, k = threadIdx.x;
        red[k] = sh[k] * W[(size_t)k * 256 + n];
        __syncthreads();
        for (int off = 128; off > 0; off >>= 1) {
            if (k < off) red[k] += red[k + off];
            __syncthreads();
        }
        if (k == 0) cvec[n] = red[0];
    } else {
        int n = b - (has_bn ? 288 : 32);   // 0..7
        int h = n >> 1;
        const float* a = (n & 1) ? ar : al;
        int k = threadIdx.x;
        float raw = 0.f;
#pragma unroll 8
        for (int d = 0; d < 64; d++)
            raw += W[(size_t)k * 256 + 64 * h + d] * a[h * 64 + d];
        float val = (sc ? sc[k] : 1.f) * raw;
        int kc = k >> 5, rem = k & 31, q = rem >> 3, t = rem & 7;  // k = kc*32+q*8+t
        wlrfrag[kc * 512 + (q * 16 + n) * 8 + t] = f2bf(val);
        wlrfrag[kc * 512 + (q * 16 + n + 8) * 8 + t] = 0;   // zero the unused col
        __shared__ float red[256];
        red[k] = sh ? sh[k] * raw : 0.f;
        __syncthreads();
        for (int off = 128; off > 0; off >>= 1) {
            if (k < off) red[k] += red[k + off];
            __syncthreads();
        }
        if (k == 0) offlr[n] = red[0];
    }
}

// ---------------- GEMM: feat = A @ Wfrag (+cvec); el/er via extra MFMA --------
// feat16 (and hbuf) SLICE-MAJOR [slice=ch/32][node][32ch]; el/er row-major [n][4]
// (k_wgt reads them as float4 per node). af32==0 input (hbuf) is slice-major.
__launch_bounds__(256)
__global__ void k_gemm(const void* __restrict__ Araw, int af32,
                       const unsigned short* __restrict__ Wfrag,
                       const float* __restrict__ cvec,
                       const unsigned short* __restrict__ wlrfrag,
                       const float* __restrict__ offlr,
                       unsigned short* __restrict__ feat16, float* __restrict__ el,
                       float* __restrict__ er) {
    constexpr int AP = 264;  // A lds pitch in bf16 elems (row start 16B-aligned)
    __shared__ __align__(16) unsigned short Alds[64 * AP];
    const int tid = threadIdx.x;
    const int rowbase = blockIdx.x * 64;

    // stage A: 64 rows x 256 bf16
    if (af32) {
        const float* A = (const float*)Araw;
        int r = tid >> 6;
        int c4 = tid & 63;
        for (int it = 0; it < 16; it++) {
            int rr = it * 4 + r;
            int gr = rowbase + rr;
            float4 v = make_float4(0.f, 0.f, 0.f, 0.f);
            if (gr < NN) v = *(const float4*)(A + (size_t)gr * 256 + c4 * 4);
            ushort4 pv;
            pv.x = f2bf(v.x); pv.y = f2bf(v.y); pv.z = f2bf(v.z); pv.w = f2bf(v.w);
            *(ushort4*)(&Alds[rr * AP + c4 * 4]) = pv;
        }
    } else {
        const unsigned short* A = (const unsigned short*)Araw;
        for (int it = 0; it < 8; it++) {
            int idx = it * 256 + tid;
            int rr = idx >> 5;
            int c16 = idx & 31;
            int gr = rowbase + rr;
            uint4 v = make_uint4(0u, 0u, 0u, 0u);
            if (gr < NN)
                v = *(const uint4*)(A + ((size_t)(c16 >> 2) * NN + gr) * 32 + (c16 & 3) * 8);
            *(uint4*)(&Alds[rr * AP + c16 * 8]) = v;
        }
    }
    __syncthreads();

    f32x4 acc[4][4];
    for (int i = 0; i < 4; i++)
        for (int j = 0; j < 4; j++)
            acc[i][j] = (f32x4){0.f, 0.f, 0.f, 0.f};
    f32x4 accLR[4];
    for (int i = 0; i < 4; i++) accLR[i] = (f32x4){0.f, 0.f, 0.f, 0.f};

    const int lane = tid & 63, w = tid >> 6;
    const int mm = lane & 15, q = lane >> 4;

    const unsigned short* bbase = Wfrag + ((size_t)w * 8 * 4) * 512 + (size_t)lane * 8;

#pragma unroll
    for (int kc = 0; kc < 8; kc++) {
        bf16x8 a[4], b[4];
        for (int i = 0; i < 4; i++)
            a[i] = *(const bf16x8*)(&Alds[(16 * i + mm) * AP + kc * 32 + q * 8]);
        for (int j = 0; j < 4; j++)
            b[j] = *(const bf16x8*)(bbase + (size_t)(kc * 4 + j) * 512);
        for (int i = 0; i < 4; i++)
            for (int j = 0; j < 4; j++)
                acc[i][j] = __builtin_amdgcn_mfma_f32_16x16x32_bf16(a[i], b[j], acc[i][j], 0, 0, 0);
        if (w == 0) {
            bf16x8 blr = *(const bf16x8*)(wlrfrag + kc * 512 + lane * 8);
            for (int i = 0; i < 4; i++)
                accLR[i] = __builtin_amdgcn_mfma_f32_16x16x32_bf16(a[i], blr, accLR[i], 0, 0, 0);
        }
    }
    __syncthreads();   // all waves done reading Alds before epilogue reuses it

    // ---- folded-BN column offset on feat ----
    if (cvec) {
        float cv[4];
        for (int j = 0; j < 4; j++) cv[j] = cvec[64 * w + 16 * j + mm];
        for (int i = 0; i < 4; i++)
            for (int j = 0; j < 4; j++)
                for (int r = 0; r < 4; r++)
                    acc[i][j][r] += cv[j];
    }

    // ---- el/er write (wave 0, C-layout col=mm -> n=2h+s); row-major [n][4] ----
    if (w == 0 && mm < 8) {
        float off = offlr[mm];
        int h = mm >> 1;
        float* dstp = (mm & 1) ? er : el;
        for (int i = 0; i < 4; i++)
            for (int r = 0; r < 4; r++) {
                int gr = rowbase + 16 * i + q * 4 + r;
                if (gr < NN) dstp[gr * 4 + h] = accLR[i][r] + off;
            }
    }

    // ---- LDS-bounce feat16 store, SLICE-MAJOR layout ----
    for (int i = 0; i < 4; i++)
        for (int j = 0; j < 4; j++) {
            int gc = 64 * w + 16 * j + mm;
            for (int r = 0; r < 4; r++) {
                int rr = 16 * i + q * 4 + r;
                Alds[rr * AP + gc] = f2bf(acc[i][j][r]);
            }
        }
    __syncthreads();
    for (int it = 0; it < 8; it++) {
        int idx = it * 256 + tid;
        int rr = idx >> 5;
        int c16 = idx & 31;
        int gr = rowbase + rr;
        if (gr < NN) {
            int s = c16 >> 2, cc = c16 & 3;
            *(uint4*)(feat16 + ((size_t)s * NN + gr) * 32 + cc * 8) =
                *(const uint4*)(&Alds[rr * AP + c16 * 8]);
        }
    }
}

// ---------------- edge-parallel attention weights, HEAD-MAJOR [4][NE] ----------
// One thread per CSR slot; coalesced wgt writes per head; one exp per (edge,head).
__global__ void k_wgt(const unsigned short* __restrict__ ssrc,
                      const unsigned short* __restrict__ sdst,
                      const float* __restrict__ el, const float* __restrict__ er,
                      float* __restrict__ wgt) {
    int i = blockIdx.x * 256 + threadIdx.x;
    if (i >= NE) return;
    int s = ssrc[i], dd = sdst[i];
    float4 a = *(const float4*)(el + (size_t)s * 4);
    float4 b = *(const float4*)(er + (size_t)dd * 4);
    float v;
    v = a.x + b.x; v = (v > 0.f) ? v : SLOPE_A * v; wgt[0 * (size_t)NE + i] = __expf(v);
    v = a.y + b.y; v = (v > 0.f) ? v : SLOPE_A * v; wgt[1 * (size_t)NE + i] = __expf(v);
    v = a.z + b.z; v = (v > 0.f) ? v : SLOPE_A * v; wgt[2 * (size_t)NE + i] = __expf(v);
    v = a.w + b.w; v = (v > 0.f) ? v : SLOPE_A * v; wgt[3 * (size_t)NE + i] = __expf(v);
}

// ---------------- XCD-sharded aggregation, zero-reduce form ----------------
// Slice s (32ch) preferred by blocks whose HW XCC id == s (steal fallback over
// all slices: correct under ANY xcc values). Hierarchical queues: 8 sub-counters
// per slice (node ranges of 6250) kill atomic contention; wave grabs 32 nodes.
// Wave layout: 16 node-groups x 4 lanes (ck = 16B chunk). Each group walks its
// node's WHOLE edge list (4-deep unroll: 4 independent 16B gathers in flight),
// weight stream wgt[h][beg..end) is sequential, NO el gather, NO exp, NO shfl
// reduce (each lane owns its 8 channels end-to-end). Epilogue store is a
// contiguous 1KB per wave (slice-major out).
__launch_bounds__(256)
__global__ void k_aggx(const unsigned short* __restrict__ featS,
                       const float* __restrict__ wgt,
                       const int* __restrict__ rowptr, const unsigned short* __restrict__ ssrc,
                       const unsigned short* __restrict__ residh, const float* __restrict__ residf,
                       const float* __restrict__ bnscale, const float* __restrict__ bnshift,
                       int use_bn, const float* __restrict__ bias, int act,
                       unsigned short* __restrict__ outh, float* __restrict__ poutf,
                       int final_mean, int* __restrict__ qcnt) {
    int xcc;
    asm volatile("s_getreg_b32 %0, hwreg(20, 0, 32)" : "=s"(xcc));
    xcc &= 7;
    const int l = threadIdx.x & 63;
    const int wave = threadIdx.x >> 6;
    const int g = l >> 2;          // node group 0..15
    const int ck = l & 3;          // 16B chunk of the 64B slice row
    const int jstart = ((blockIdx.x >> 3) + wave) & 7;

    for (int s0 = 0; s0 < 8; s0++) {
        int s = (xcc + s0) & 7;
        int h = s >> 1;
        const unsigned short* fs = featS + (size_t)s * NN * 32;
        const unsigned short* rs = residh ? residh + (size_t)s * NN * 32 : (const unsigned short*)0;
        const float* wh = wgt + (size_t)h * NE;
        const int coff = s * 32 + ck * 8;
        for (int j0 = 0; j0 < 8; j0++) {
            int j = (jstart + j0) & 7;
            int nbase = j * SUBN;
            int* qc = qcnt + (s * 8 + j) * 16;
            while (true) {
                int b = 0;
                if (l == 0) b = atomicAdd(qc, 32);
                b = __shfl(b, 0, 64);
                if (b >= SUBN) break;
                for (int half = 0; half < 2; half++) {
                    int ofs = b + half * 16 + g;
                    bool valid = ofs < SUBN;
                    int n = nbase + (valid ? ofs : 0);
                    int beg = rowptr[n], end = rowptr[n + 1];
                    if (!valid) end = beg;
                    float d = 0.f;
                    float acc[8];
#pragma unroll
                    for (int k = 0; k < 8; k++) acc[k] = 0.f;
                    for (int e = beg; e < end; e += 4) {
                        int ss4[4];
                        float wg4[4];
                        uint4 ff[4];
#pragma unroll
                        for (int u = 0; u < 4; u++) {
                            int idx = e + u;
                            int cidx = (idx < end) ? idx : beg;
                            ss4[u] = ssrc[cidx];
                            float wv = wh[cidx];
                            wg4[u] = (idx < end) ? wv : 0.f;
                        }
#pragma unroll
                        for (int u = 0; u < 4; u++)
                            ff[u] = *(const uint4*)(fs + (size_t)ss4[u] * 32 + ck * 8);
#pragma unroll
                        for (int u = 0; u < 4; u++) {
                            float w = wg4[u];
                            d += w;
                            acc[0] += bflo(ff[u].x) * w; acc[1] += bfhi(ff[u].x) * w;
                            acc[2] += bflo(ff[u].y) * w; acc[3] += bfhi(ff[u].y) * w;
                            acc[4] += bflo(ff[u].z) * w; acc[5] += bfhi(ff[u].z) * w;
                            acc[6] += bflo(ff[u].w) * w; acc[7] += bfhi(ff[u].w) * w;
                        }
                    }
                    if (valid) {
                        float invd = 1.f / fmaxf(d, 1e-9f);
                        float v[8];
#pragma unroll
                        for (int k = 0; k < 8; k++) v[k] = acc[k] * invd;
                        float rr[8];
                        if (residf) {
                            float4 r0 = *(const float4*)(residf + (size_t)n * 256 + coff);
                            float4 r1 = *(const float4*)(residf + (size_t)n * 256 + coff + 4);
                            rr[0] = r0.x; rr[1] = r0.y; rr[2] = r0.z; rr[3] = r0.w;
                            rr[4] = r1.x; rr[5] = r1.y; rr[6] = r1.z; rr[7] = r1.w;
                        } else {
                            uint4 rv = *(const uint4*)(rs + (size_t)n * 32 + ck * 8);
                            rr[0] = bflo(rv.x); rr[1] = bfhi(rv.x);
                            rr[2] = bflo(rv.y); rr[3] = bfhi(rv.y);
                            rr[4] = bflo(rv.z); rr[5] = bfhi(rv.z);
                            rr[6] = bflo(rv.w); rr[7] = bfhi(rv.w);
                        }
                        if (use_bn) {
                            float4 s0v = *(const float4*)(bnscale + coff);
                            float4 s1v = *(const float4*)(bnscale + coff + 4);
                            float4 h0v = *(const float4*)(bnshift + coff);
                            float4 h1v = *(const float4*)(bnshift + coff + 4);
                            rr[0] = rr[0] * s0v.x + h0v.x; rr[1] = rr[1] * s0v.y + h0v.y;
                            rr[2] = rr[2] * s0v.z + h0v.z; rr[3] = rr[3] * s0v.w + h0v.w;
                            rr[4] = rr[4] * s1v.x + h1v.x; rr[5] = rr[5] * s1v.y + h1v.y;
                            rr[6] = rr[6] * s1v.z + h1v.z; rr[7] = rr[7] * s1v.w + h1v.w;
                        }
                        float4 b0 = *(const float4*)(bias + coff);
                        float4 b1 = *(const float4*)(bias + coff + 4);
                        v[0] += rr[0] + b0.x; v[1] += rr[1] + b0.y;
                        v[2] += rr[2] + b0.z; v[3] += rr[3] + b0.w;
                        v[4] += rr[4] + b1.x; v[5] += rr[5] + b1.y;
                        v[6] += rr[6] + b1.z; v[7] += rr[7] + b1.w;
                        if (act) {
#pragma unroll
                            for (int k = 0; k < 8; k++)
                                v[k] = (v[k] > 0.f) ? v[k] : SLOPE_R * v[k];
                        }
                        if (!final_mean) {
                            uint4 o;
                            o.x = (unsigned)f2bf(v[0]) | ((unsigned)f2bf(v[1]) << 16);
                            o.y = (unsigned)f2bf(v[2]) | ((unsigned)f2bf(v[3]) << 16);
                            o.z = (unsigned)f2bf(v[4]) | ((unsigned)f2bf(v[5]) << 16);
                            o.w = (unsigned)f2bf(v[6]) | ((unsigned)f2bf(v[7]) << 16);
                            *(uint4*)(outh + ((size_t)s * NN + n) * 32 + ck * 8) = o;
                        } else {
                            float* pp = poutf + ((size_t)s * NN + n) * 32 + ck * 8;
                            *(float4*)pp = make_float4(v[0], v[1], v[2], v[3]);
                            *(float4*)(pp + 4) = make_float4(v[4], v[5], v[6], v[7]);
                        }
                    }
                }
            }
        }
    }
}

// ---------------- head-mean of the per-slice partials (final layer) ----------
__global__ void k_mean(const float* __restrict__ pout, float* __restrict__ out) {
    int i = blockIdx.x * 256 + threadIdx.x;
    if (i >= NN * 16) return;
    int n = i >> 4;
    int c4 = (i & 15) * 4;          // dd base, multiple of 4
    int par = (c4 >= 32) ? 1 : 0;
    int cc = c4 & 31;
    float4 sum = make_float4(0.f, 0.f, 0.f, 0.f);
#pragma unroll
    for (int j = 0; j < 4; j++) {
        int s = 2 * j + par;
        float4 v = *(const float4*)(pout + ((size_t)s * NN + n) * 32 + cc);
        sum.x += v.x; sum.y += v.y; sum.z += v.z; sum.w += v.w;
    }
    sum.x *= 0.25f; sum.y *= 0.25f; sum.z *= 0.25f; sum.w *= 0.25f;
    *(float4*)(out + (size_t)n * 64 + c4) = sum;
}

// ---------------- BatchNorm stats over slice-major hbuf ----------------
__global__ void k_bnstats(const unsigned short* __restrict__ hh, float* __restrict__ pbuf) {
    __shared__ float ps[8 * 256];
    __shared__ float ps2[8 * 256];
    int t = threadIdx.x, b = blockIdx.x;
    int r8 = t >> 5, c32 = t & 31;
    int sl = c32 >> 2, cc = (c32 & 3) * 8;
    int r0 = b * 196, r1 = min(r0 + 196, NN);
    float s[8], s2[8];
#pragma unroll
    for (int e = 0; e < 8; e++) { s[e] = 0.f; s2[e] = 0.f; }
    for (int r = r0 + r8; r < r1; r += 8) {
        uint4 v = *(const uint4*)(hh + ((size_t)sl * NN + r) * 32 + cc);
        const unsigned short* pv = (const unsigned short*)&v;
#pragma unroll
        for (int e = 0; e < 8; e++) {
            float f = bf2f(pv[e]);
            s[e] += f; s2[e] += f * f;
        }
    }
#pragma unroll
    for (int e = 0; e < 8; e++) {
        ps[r8 * 256 + c32 * 8 + e] = s[e];
        ps2[r8 * 256 + c32 * 8 + e] = s2[e];
    }
    __syncthreads();
    float ts = 0.f, ts2 = 0.f;
    for (int g = 0; g < 8; g++) { ts += ps[g * 256 + t]; ts2 += ps2[g * 256 + t]; }
    pbuf[b * 512 + t] = ts;
    pbuf[b * 512 + 256 + t] = ts2;
}

__global__ void k_bnfinal(const float* __restrict__ pbuf, const float* __restrict__ g,
                          const float* __restrict__ be, float* __restrict__ scale,
                          float* __restrict__ shift) {
    int t = threadIdx.x;
    float s = 0.f, s2 = 0.f;
    for (int b = 0; b < 256; b++) {
        s += pbuf[b * 512 + t];
        s2 += pbuf[b * 512 + 256 + t];
    }
    float mu = s * (1.f / NN);
    float var = s2 * (1.f / NN) - mu * mu;
    float rs = rsqrtf(var + 1e-5f);
    float sc = rs * g[t];
    scale[t] = sc;
    shift[t] = be[t] - mu * sc;
}

// ---------------- launcher ----------------
extern "C" void kernel_launch(void* const* d_in, const int* in_sizes, int n_in,
                              void* d_out, int out_size, void* d_ws, size_t ws_size,
                              hipStream_t stream) {
    const float* x   = (const float*)d_in[0];
    const int* src   = (const int*)d_in[1];
    const int* dst   = (const int*)d_in[2];
    const float* W1  = (const float*)d_in[3];
    const float* al1 = (const float*)d_in[4];
    const float* ar1 = (const float*)d_in[5];
    const float* b1  = (const float*)d_in[6];
    const float* W2  = (const float*)d_in[7];
    const float* al2 = (const float*)d_in[8];
    const float* ar2 = (const float*)d_in[9];
    const float* b2  = (const float*)d_in[10];
    const float* W3  = (const float*)d_in[11];
    const float* al3 = (const float*)d_in[12];
    const float* ar3 = (const float*)d_in[13];
    const float* b3  = (const float*)d_in[14];
    const float* g1  = (const float*)d_in[15];
    const float* be1 = (const float*)d_in[16];
    const float* g2  = (const float*)d_in[17];
    const float* be2 = (const float*)d_in[18];
    float* out = (float*)d_out;

    char* ws = (char*)d_ws;
    size_t off = 0;
    auto alloc = [&](size_t bytes) {
        void* p = ws + off;
        off += (bytes + 255) & ~(size_t)255;
        return p;
    };
    int* rowptr = (int*)alloc((NN + 1) * sizeof(int));
    int* cursor = (int*)alloc(NN * sizeof(int));
    int* cnt    = (int*)alloc(SCB * 256 * sizeof(int));
    int* loc    = (int*)alloc(SCB * 256 * sizeof(int));
    int* bsum   = (int*)alloc(SCB * sizeof(int));
    int* boff   = (int*)alloc(SCB * sizeof(int));
    int* qcnt   = (int*)alloc(3 * 64 * 16 * sizeof(int));   // 3 layers x 64 sub-queues
    unsigned short* ssrc = (unsigned short*)alloc(NE * sizeof(unsigned short));
    unsigned short* sdst = (unsigned short*)alloc(NE * sizeof(unsigned short));
    float* wgt  = (float*)alloc((size_t)4 * NE * sizeof(float));
    unsigned short* feat16 = (unsigned short*)alloc((size_t)NN * 256 * sizeof(unsigned short));
    unsigned short* hbuf   = (unsigned short*)alloc((size_t)NN * 256 * sizeof(unsigned short));
    float* el   = (float*)alloc((size_t)NN * 4 * sizeof(float));
    float* er   = (float*)alloc((size_t)NN * 4 * sizeof(float));
    float* pout = (float*)alloc((size_t)8 * NN * 32 * sizeof(float));
    unsigned short* Wfrag1  = (unsigned short*)alloc(65536 * sizeof(unsigned short));
    unsigned short* Wfrag2  = (unsigned short*)alloc(65536 * sizeof(unsigned short));
    unsigned short* wlrfrag = (unsigned short*)alloc(4096 * sizeof(unsigned short));
    float* offlr   = (float*)alloc(16 * sizeof(float));
    float* cvec    = (float*)alloc(256 * sizeof(float));
    float* pbuf    = (float*)alloc(256 * 512 * sizeof(float));
    float* bnscale = (float*)alloc(256 * sizeof(float));
    float* bnshift = (float*)alloc(256 * sizeof(float));

    // CSR build (graph identical for all layers)
    hipMemsetAsync(cnt, 0, NN * sizeof(int), stream);
    hipMemsetAsync(qcnt, 0, 3 * 64 * 16 * sizeof(int), stream);
    k_hist<<<(NE + 255) / 256, 256, 0, stream>>>(dst, cnt);
    k_scan1<<<SCB, 256, 0, stream>>>(cnt, loc, bsum);
    k_scan2<<<1, 256, 0, stream>>>(bsum, boff, rowptr);
    k_scan3<<<SCB, 256, 0, stream>>>(loc, boff, rowptr, cursor);
    k_scatter<<<(NE + 255) / 256, 256, 0, stream>>>(src, dst, cursor, ssrc, sdst);
    k_fold<<<40, 256, 0, stream>>>(W1, nullptr, nullptr, al1, ar1,
                                   Wfrag1, nullptr, wlrfrag, offlr, 0);

    const int GB = (NN + 63) / 64;  // 782
    const int EB = (NE + 255) / 256;
    const int XB = 2048;

    // ---- layer 1 ----
    k_gemm<<<GB, 256, 0, stream>>>(x, 1, Wfrag1, nullptr, wlrfrag, offlr, feat16, el, er);
    k_wgt<<<EB, 256, 0, stream>>>(ssrc, sdst, el, er, wgt);
    k_aggx<<<XB, 256, 0, stream>>>(feat16, wgt, rowptr, ssrc, nullptr, x,
                                   nullptr, nullptr, 0, b1, 1, hbuf, nullptr, 0, qcnt);
    k_bnstats<<<256, 256, 0, stream>>>(hbuf, pbuf);
    k_bnfinal<<<1, 256, 0, stream>>>(pbuf, g1, be1, bnscale, bnshift);
    k_fold<<<296, 256, 0, stream>>>(W2, bnscale, bnshift, al2, ar2,
                                    Wfrag2, cvec, wlrfrag, offlr, 1);

    // ---- layer 2 ----
    k_gemm<<<GB, 256, 0, stream>>>(hbuf, 0, Wfrag2, cvec, wlrfrag, offlr, feat16, el, er);
    k_wgt<<<EB, 256, 0, stream>>>(ssrc, sdst, el, er, wgt);
    k_aggx<<<XB, 256, 0, stream>>>(feat16, wgt, rowptr, ssrc, hbuf, nullptr,
                                   bnscale, bnshift, 1, b2, 1, hbuf, nullptr, 0, qcnt + 1024);
    k_bnstats<<<256, 256, 0, stream>>>(hbuf, pbuf);
    k_bnfinal<<<1, 256, 0, stream>>>(pbuf, g2, be2, bnscale, bnshift);
    k_fold<<<296, 256, 0, stream>>>(W3, bnscale, bnshift, al3, ar3,
                                    Wfrag2, cvec, wlrfrag, offlr, 1);

    // ---- layer 3 ----
    k_gemm<<<GB, 256, 0, stream>>>(hbuf, 0, Wfrag2, cvec, wlrfrag, offlr, feat16, el, er);
    k_wgt<<<EB, 256, 0, stream>>>(ssrc, sdst, el, er, wgt);
    k_aggx<<<XB, 256, 0, stream>>>(feat16, wgt, rowptr, ssrc, hbuf, nullptr,
                                   bnscale, bnshift, 1, b3, 0, nullptr, pout, 1, qcnt + 2048);
    k_mean<<<(NN * 16 + 255) / 256, 256, 0, stream>>>(pout, out);
}

// Round 9
// 549.270 us; speedup vs baseline: 2.4403x; 1.9167x over previous
//
#include <hip/hip_runtime.h>

constexpr int NN = 50000;     // nodes
constexpr int NE = 800000;    // edges
constexpr float SLOPE_A = 0.2f;   // attention leaky_relu
constexpr float SLOPE_R = 0.01f;  // activation leaky_relu
constexpr int SCB = 196;      // scan blocks: 196*256 = 50176 >= NN

typedef __attribute__((ext_vector_type(8))) short bf16x8;
typedef __attribute__((ext_vector_type(4))) float f32x4;

__device__ __forceinline__ unsigned short f2bf(float f) {
    union { float f; unsigned u; } v; v.f = f;
    unsigned u = v.u;
    unsigned r = u + 0x7fffu + ((u >> 16) & 1u);  // round-to-nearest-even
    return (unsigned short)(r >> 16);
}
__device__ __forceinline__ float bf2f(unsigned short s) {
    union { unsigned u; float f; } v; v.u = ((unsigned)s) << 16;
    return v.f;
}
// low/high bf16 halves of a packed u32 -> f32 (1 VALU op each)
__device__ __forceinline__ float bflo(unsigned u) {
    union { unsigned u; float f; } v; v.u = u << 16; return v.f;
}
__device__ __forceinline__ float bfhi(unsigned u) {
    union { unsigned u; float f; } v; v.u = u & 0xffff0000u; return v.f;
}

// ---------------- CSR build ----------------
__global__ void k_hist(const int* __restrict__ dst, int* __restrict__ cnt) {
    int i = blockIdx.x * 256 + threadIdx.x;
    if (i < NE) atomicAdd(&cnt[dst[i]], 1);
}

__global__ void k_scan1(const int* __restrict__ cnt, int* __restrict__ loc,
                        int* __restrict__ bsum) {
    __shared__ int sh[256];
    int t = threadIdx.x;
    int i = blockIdx.x * 256 + t;
    int v = (i < NN) ? cnt[i] : 0;
    sh[t] = v;
    __syncthreads();
    for (int off = 1; off < 256; off <<= 1) {
        int tmp = (t >= off) ? sh[t - off] : 0;
        __syncthreads();
        sh[t] += tmp;
        __syncthreads();
    }
    loc[i] = sh[t] - v;
    if (t == 255) bsum[blockIdx.x] = sh[255];
}

__global__ void k_scan2(const int* __restrict__ bsum, int* __restrict__ boff,
                        int* __restrict__ rowptr) {
    __shared__ int sh[256];
    int t = threadIdx.x;
    int v = (t < SCB) ? bsum[t] : 0;
    sh[t] = v;
    __syncthreads();
    for (int off = 1; off < 256; off <<= 1) {
        int tmp = (t >= off) ? sh[t - off] : 0;
        __syncthreads();
        sh[t] += tmp;
        __syncthreads();
    }
    if (t < SCB) boff[t] = sh[t] - v;
    if (t == 255) rowptr[NN] = sh[255];
}

__global__ void k_scan3(const int* __restrict__ loc, const int* __restrict__ boff,
                        int* __restrict__ rowptr, int* __restrict__ cursor) {
    int i = blockIdx.x * 256 + threadIdx.x;
    if (i < NN) {
        int r = loc[i] + boff[blockIdx.x];
        rowptr[i] = r;
        cursor[i] = r;
    }
}

// src ids fit in 16 bits (NN < 65536): halves the sorted-src index stream
__global__ void k_scatter(const int* __restrict__ src, const int* __restrict__ dst,
                          int* __restrict__ cursor, unsigned short* __restrict__ ssrc) {
    int i = blockIdx.x * 256 + threadIdx.x;
    if (i < NE) {
        int d = dst[i];
        int pos = atomicAdd(&cursor[d], 1);
        ssrc[pos] = (unsigned short)src[i];
    }
}

// ---------------- fold: Wfrag + cvec + wl/wr fragment + offlr, all from fp32 W ----
// has_bn=1 grid 296: b<32 Wfrag | 32..287 cvec | 288..295 lr-fold (n=b-288)
// has_bn=0 grid  40: b<32 Wfrag | 32..39 lr-fold (n=b-32)
__global__ void k_fold(const float* __restrict__ W, const float* __restrict__ sc,
                       const float* __restrict__ sh, const float* __restrict__ al,
                       const float* __restrict__ ar, unsigned short* __restrict__ Wfrag,
                       float* __restrict__ cvec, unsigned short* __restrict__ wlrfrag,
                       float* __restrict__ offlr, int has_bn) {
    int b = blockIdx.x;
    if (b < 32) {
        int gid = b * 256 + threadIdx.x;   // < 8192; one thread = 8 shorts
        int lane = gid & 63;
        int frag = gid >> 6;               // 0..127
        int j = frag & 3, kc = (frag >> 2) & 7, w = frag >> 5;
        int mm = lane & 15, q = lane >> 4;
        int n = 64 * w + 16 * j + mm;
        int k0 = kc * 32 + q * 8;
        unsigned short o[8];
#pragma unroll
        for (int t = 0; t < 8; t++) {
            float wv = W[(size_t)(k0 + t) * 256 + n];
            if (sc) wv *= sc[k0 + t];
            o[t] = f2bf(wv);
        }
        *(uint4*)(Wfrag + (size_t)gid * 8) = *(const uint4*)o;
    } else if (has_bn && b < 288) {
        __shared__ float red[256];
        int n = b - 32, k = threadIdx.x;
        red[k] = sh[k] * W[(size_t)k * 256 + n];
        __syncthreads();
        for (int off = 128; off > 0; off >>= 1) {
            if (k < off) red[k] += red[k + off];
            __syncthreads();
        }
        if (k == 0) cvec[n] = red[0];
    } else {
        int n = b - (has_bn ? 288 : 32);   // 0..7
        int h = n >> 1;
        const float* a = (n & 1) ? ar : al;
        int k = threadIdx.x;
        float raw = 0.f;
#pragma unroll 8
        for (int d = 0; d < 64; d++)
            raw += W[(size_t)k * 256 + 64 * h + d] * a[h * 64 + d];
        float val = (sc ? sc[k] : 1.f) * raw;
        int kc = k >> 5, rem = k & 31, q = rem >> 3, t = rem & 7;  // k = kc*32+q*8+t
        wlrfrag[kc * 512 + (q * 16 + n) * 8 + t] = f2bf(val);
        wlrfrag[kc * 512 + (q * 16 + n + 8) * 8 + t] = 0;   // zero the unused col
        __shared__ float red[256];
        red[k] = sh ? sh[k] * raw : 0.f;
        __syncthreads();
        for (int off = 128; off > 0; off >>= 1) {
            if (k < off) red[k] += red[k + off];
            __syncthreads();
        }
        if (k == 0) offlr[n] = red[0];
    }
}

// ---------------- GEMM: feat = A @ Wfrag (+cvec); el/er via extra MFMA --------
// block: 256 thr = 4 waves; tile 64 rows x 256 cols; wave w owns cols [64w,64w+64).
// Wave 0 additionally computes the 8-col el/er matvec with one extra B-frag.
__launch_bounds__(256)
__global__ void k_gemm(const void* __restrict__ Araw, int af32,
                       const unsigned short* __restrict__ Wfrag,
                       const float* __restrict__ cvec,
                       const unsigned short* __restrict__ wlrfrag,
                       const float* __restrict__ offlr,
                       unsigned short* __restrict__ feat16, float* __restrict__ el,
                       float* __restrict__ er) {
    constexpr int AP = 264;  // A lds pitch in bf16 elems (row start 16B-aligned)
    __shared__ __align__(16) unsigned short Alds[64 * AP];
    const int tid = threadIdx.x;
    const int rowbase = blockIdx.x * 64;

    // stage A: 64 rows x 256 bf16
    if (af32) {
        const float* A = (const float*)Araw;
        int r = tid >> 6;
        int c4 = tid & 63;
        for (int it = 0; it < 16; it++) {
            int rr = it * 4 + r;
            int gr = rowbase + rr;
            float4 v = make_float4(0.f, 0.f, 0.f, 0.f);
            if (gr < NN) v = *(const float4*)(A + (size_t)gr * 256 + c4 * 4);
            ushort4 pv;
            pv.x = f2bf(v.x); pv.y = f2bf(v.y); pv.z = f2bf(v.z); pv.w = f2bf(v.w);
            *(ushort4*)(&Alds[rr * AP + c4 * 4]) = pv;
        }
    } else {
        const unsigned short* A = (const unsigned short*)Araw;
        for (int it = 0; it < 8; it++) {
            int idx = it * 256 + tid;
            int rr = idx >> 5;
            int c16 = idx & 31;
            int gr = rowbase + rr;
            uint4 v = make_uint4(0u, 0u, 0u, 0u);
            if (gr < NN) v = *(const uint4*)(A + (size_t)gr * 256 + c16 * 8);
            *(uint4*)(&Alds[rr * AP + c16 * 8]) = v;
        }
    }
    __syncthreads();

    f32x4 acc[4][4];
    for (int i = 0; i < 4; i++)
        for (int j = 0; j < 4; j++)
            acc[i][j] = (f32x4){0.f, 0.f, 0.f, 0.f};
    f32x4 accLR[4];
    for (int i = 0; i < 4; i++) accLR[i] = (f32x4){0.f, 0.f, 0.f, 0.f};

    const int lane = tid & 63, w = tid >> 6;
    const int mm = lane & 15, q = lane >> 4;

    const unsigned short* bbase = Wfrag + ((size_t)w * 8 * 4) * 512 + (size_t)lane * 8;

#pragma unroll
    for (int kc = 0; kc < 8; kc++) {
        bf16x8 a[4], b[4];
        for (int i = 0; i < 4; i++)
            a[i] = *(const bf16x8*)(&Alds[(16 * i + mm) * AP + kc * 32 + q * 8]);
        for (int j = 0; j < 4; j++)
            b[j] = *(const bf16x8*)(bbase + (size_t)(kc * 4 + j) * 512);
        for (int i = 0; i < 4; i++)
            for (int j = 0; j < 4; j++)
                acc[i][j] = __builtin_amdgcn_mfma_f32_16x16x32_bf16(a[i], b[j], acc[i][j], 0, 0, 0);
        if (w == 0) {
            bf16x8 blr = *(const bf16x8*)(wlrfrag + kc * 512 + lane * 8);
            for (int i = 0; i < 4; i++)
                accLR[i] = __builtin_amdgcn_mfma_f32_16x16x32_bf16(a[i], blr, accLR[i], 0, 0, 0);
        }
    }
    __syncthreads();   // all waves done reading Alds before epilogue reuses it

    // ---- folded-BN column offset on feat ----
    if (cvec) {
        float cv[4];
        for (int j = 0; j < 4; j++) cv[j] = cvec[64 * w + 16 * j + mm];
        for (int i = 0; i < 4; i++)
            for (int j = 0; j < 4; j++)
                for (int r = 0; r < 4; r++)
                    acc[i][j][r] += cv[j];
    }

    // ---- el/er write (wave 0, C-layout col=mm -> n=2h+s) ----
    if (w == 0 && mm < 8) {
        float off = offlr[mm];
        int h = mm >> 1;
        float* dstp = (mm & 1) ? er : el;
        for (int i = 0; i < 4; i++)
            for (int r = 0; r < 4; r++) {
                int gr = rowbase + 16 * i + q * 4 + r;
                if (gr < NN) dstp[gr * 4 + h] = accLR[i][r] + off;
            }
    }

    // ---- LDS-bounce feat16 store (C/D layout: col=lane&15, row=(lane>>4)*4+reg) ----
    for (int i = 0; i < 4; i++)
        for (int j = 0; j < 4; j++) {
            int gc = 64 * w + 16 * j + mm;
            for (int r = 0; r < 4; r++) {
                int rr = 16 * i + q * 4 + r;
                Alds[rr * AP + gc] = f2bf(acc[i][j][r]);
            }
        }
    __syncthreads();
    for (int it = 0; it < 8; it++) {
        int idx = it * 256 + tid;
        int rr = idx >> 5;
        int c16 = idx & 31;
        int gr = rowbase + rr;
        if (gr < NN)
            *(uint4*)(feat16 + (size_t)gr * 256 + c16 * 8) = *(const uint4*)(&Alds[rr * AP + c16 * 8]);
    }
}

// ---------------- per-dst softmax + weighted aggregation (bf16 gather) ----------------
// ONE wave per destination node; R1-proven structure (3.74 TB/s effective).
// Lane l: edge parity p = l>>5, channel group q = l&31 (8 ch, 16B gathers).
// Per 8-edge chunk: 4 direct-addressed 16B feat gathers in flight per lane.
// Attention weight computed INLINE per lane (el gather + exp, redundant x8 per
// head): redundancy is free (R0 evidence), and no wgt stream bytes, no
// cross-lane ops anywhere in the loop (R2/R3 lesson).
__launch_bounds__(256)
__global__ void k_agg(const unsigned short* __restrict__ feat16,
                      const float* __restrict__ el, const float* __restrict__ er,
                      const int* __restrict__ rowptr, const unsigned short* __restrict__ ssrc,
                      const unsigned short* __restrict__ residh, const float* __restrict__ residf,
                      const float* __restrict__ bnscale, const float* __restrict__ bnshift,
                      int use_bn, const float* __restrict__ bias, int act,
                      unsigned short* __restrict__ outh, float* __restrict__ outf,
                      int final_mean) {
    int n = __builtin_amdgcn_readfirstlane(blockIdx.x * 4 + (threadIdx.x >> 6));
    int l = threadIdx.x & 63;
    int p = l >> 5;            // edge parity
    int q = l & 31;            // channel group
    int c8 = q * 8;            // channels [c8, c8+8)
    int hh = q >> 3;           // head of this channel group
    int beg = rowptr[n], end = rowptr[n + 1];
    float erh = er[n * 4 + hh];

    // hoisted epilogue operands (issue loads early, consume after the loop)
    float r[8];
    if (residf) {
        float4 r0 = *(const float4*)(residf + (size_t)n * 256 + c8);
        float4 r1 = *(const float4*)(residf + (size_t)n * 256 + c8 + 4);
        r[0] = r0.x; r[1] = r0.y; r[2] = r0.z; r[3] = r0.w;
        r[4] = r1.x; r[5] = r1.y; r[6] = r1.z; r[7] = r1.w;
    } else {
        uint4 rv = *(const uint4*)(residh + (size_t)n * 256 + c8);
        r[0] = bflo(rv.x); r[1] = bfhi(rv.x);
        r[2] = bflo(rv.y); r[3] = bfhi(rv.y);
        r[4] = bflo(rv.z); r[5] = bfhi(rv.z);
        r[6] = bflo(rv.w); r[7] = bfhi(rv.w);
    }

    float d = 0.f;
    float acc[8];
#pragma unroll
    for (int k = 0; k < 8; k++) acc[k] = 0.f;

    for (int e = beg; e < end; e += 8) {
        int ss[4];
#pragma unroll
        for (int j = 0; j < 4; j++) {
            int idx = e + 2 * j + p;
            ss[j] = ssrc[(idx < end) ? idx : beg];
        }
        float aa[4];
#pragma unroll
        for (int j = 0; j < 4; j++)
            aa[j] = el[ss[j] * 4 + hh];
        uint4 ff[4];
#pragma unroll
        for (int j = 0; j < 4; j++)
            ff[j] = *(const uint4*)(feat16 + (size_t)ss[j] * 256 + c8);
#pragma unroll
        for (int j = 0; j < 4; j++) {
            float sc = aa[j] + erh;
            sc = (sc > 0.f) ? sc : SLOPE_A * sc;
            float w = ((e + 2 * j + p) < end) ? __expf(sc) : 0.f;
            d += w;
            acc[0] += bflo(ff[j].x) * w; acc[1] += bfhi(ff[j].x) * w;
            acc[2] += bflo(ff[j].y) * w; acc[3] += bfhi(ff[j].y) * w;
            acc[4] += bflo(ff[j].z) * w; acc[5] += bfhi(ff[j].z) * w;
            acc[6] += bflo(ff[j].w) * w; acc[7] += bfhi(ff[j].w) * w;
        }
    }

    // combine edge parities
    d += __shfl_xor(d, 32, 64);
#pragma unroll
    for (int k = 0; k < 8; k++) acc[k] += __shfl_xor(acc[k], 32, 64);

    float invd = 1.f / fmaxf(d, 1e-9f);
#pragma unroll
    for (int k = 0; k < 8; k++) acc[k] *= invd;

    if (use_bn) {
        float4 s0 = *(const float4*)(bnscale + c8);
        float4 s1 = *(const float4*)(bnscale + c8 + 4);
        float4 h0 = *(const float4*)(bnshift + c8);
        float4 h1 = *(const float4*)(bnshift + c8 + 4);
        r[0] = r[0] * s0.x + h0.x; r[1] = r[1] * s0.y + h0.y;
        r[2] = r[2] * s0.z + h0.z; r[3] = r[3] * s0.w + h0.w;
        r[4] = r[4] * s1.x + h1.x; r[5] = r[5] * s1.y + h1.y;
        r[6] = r[6] * s1.z + h1.z; r[7] = r[7] * s1.w + h1.w;
    }
    {
        float4 b0 = *(const float4*)(bias + c8);
        float4 b1 = *(const float4*)(bias + c8 + 4);
        acc[0] += r[0] + b0.x; acc[1] += r[1] + b0.y;
        acc[2] += r[2] + b0.z; acc[3] += r[3] + b0.w;
        acc[4] += r[4] + b1.x; acc[5] += r[5] + b1.y;
        acc[6] += r[6] + b1.z; acc[7] += r[7] + b1.w;
    }
    if (act) {
#pragma unroll
        for (int k = 0; k < 8; k++) acc[k] = (acc[k] > 0.f) ? acc[k] : SLOPE_R * acc[k];
    }

    if (!final_mean) {
        if (p == 0) {
            uint4 o;
            o.x = (unsigned)f2bf(acc[0]) | ((unsigned)f2bf(acc[1]) << 16);
            o.y = (unsigned)f2bf(acc[2]) | ((unsigned)f2bf(acc[3]) << 16);
            o.z = (unsigned)f2bf(acc[4]) | ((unsigned)f2bf(acc[5]) << 16);
            o.w = (unsigned)f2bf(acc[6]) | ((unsigned)f2bf(acc[7]) << 16);
            *(uint4*)(outh + (size_t)n * 256 + c8) = o;
        }
    } else {
        // head mean: lanes q, q^8, q^16(,q^24) hold same d-channel, different heads
#pragma unroll
        for (int k = 0; k < 8; k++) {
            acc[k] += __shfl_xor(acc[k], 8, 64);
            acc[k] += __shfl_xor(acc[k], 16, 64);
        }
        if (p == 0 && q < 8) {
            float4 o0 = make_float4(acc[0] * 0.25f, acc[1] * 0.25f, acc[2] * 0.25f, acc[3] * 0.25f);
            float4 o1 = make_float4(acc[4] * 0.25f, acc[5] * 0.25f, acc[6] * 0.25f, acc[7] * 0.25f);
            *(float4*)(outf + (size_t)n * 64 + c8) = o0;
            *(float4*)(outf + (size_t)n * 64 + c8 + 4) = o1;
        }
    }
}

// ---------------- BatchNorm stats: vectorized partials, no atomics (256 blocks) ----
__global__ void k_bnstats(const unsigned short* __restrict__ hh, float* __restrict__ pbuf) {
    __shared__ float ps[8 * 256];
    __shared__ float ps2[8 * 256];
    int t = threadIdx.x, b = blockIdx.x;
    int r8 = t >> 5, c32 = t & 31;
    int r0 = b * 196, r1 = min(r0 + 196, NN);
    float s[8], s2[8];
#pragma unroll
    for (int e = 0; e < 8; e++) { s[e] = 0.f; s2[e] = 0.f; }
    for (int r = r0 + r8; r < r1; r += 8) {
        uint4 v = *(const uint4*)(hh + (size_t)r * 256 + c32 * 8);
        const unsigned short* pv = (const unsigned short*)&v;
#pragma unroll
        for (int e = 0; e < 8; e++) {
            float f = bf2f(pv[e]);
            s[e] += f; s2[e] += f * f;
        }
    }
#pragma unroll
    for (int e = 0; e < 8; e++) {
        ps[r8 * 256 + c32 * 8 + e] = s[e];
        ps2[r8 * 256 + c32 * 8 + e] = s2[e];
    }
    __syncthreads();
    float ts = 0.f, ts2 = 0.f;
    for (int g = 0; g < 8; g++) { ts += ps[g * 256 + t]; ts2 += ps2[g * 256 + t]; }
    pbuf[b * 512 + t] = ts;
    pbuf[b * 512 + 256 + t] = ts2;
}

__global__ void k_bnfinal(const float* __restrict__ pbuf, const float* __restrict__ g,
                          const float* __restrict__ be, float* __restrict__ scale,
                          float* __restrict__ shift) {
    int t = threadIdx.x;
    float s = 0.f, s2 = 0.f;
    for (int b = 0; b < 256; b++) {
        s += pbuf[b * 512 + t];
        s2 += pbuf[b * 512 + 256 + t];
    }
    float mu = s * (1.f / NN);
    float var = s2 * (1.f / NN) - mu * mu;
    float rs = rsqrtf(var + 1e-5f);
    float sc = rs * g[t];
    scale[t] = sc;
    shift[t] = be[t] - mu * sc;
}

// ---------------- launcher ----------------
extern "C" void kernel_launch(void* const* d_in, const int* in_sizes, int n_in,
                              void* d_out, int out_size, void* d_ws, size_t ws_size,
                              hipStream_t stream) {
    const float* x   = (const float*)d_in[0];
    const int* src   = (const int*)d_in[1];
    const int* dst   = (const int*)d_in[2];
    const float* W1  = (const float*)d_in[3];
    const float* al1 = (const float*)d_in[4];
    const float* ar1 = (const float*)d_in[5];
    const float* b1  = (const float*)d_in[6];
    const float* W2  = (const float*)d_in[7];
    const float* al2 = (const float*)d_in[8];
    const float* ar2 = (const float*)d_in[9];
    const float* b2  = (const float*)d_in[10];
    const float* W3  = (const float*)d_in[11];
    const float* al3 = (const float*)d_in[12];
    const float* ar3 = (const float*)d_in[13];
    const float* b3  = (const float*)d_in[14];
    const float* g1  = (const float*)d_in[15];
    const float* be1 = (const float*)d_in[16];
    const float* g2  = (const float*)d_in[17];
    const float* be2 = (const float*)d_in[18];
    float* out = (float*)d_out;

    char* ws = (char*)d_ws;
    size_t off = 0;
    auto alloc = [&](size_t bytes) {
        void* p = ws + off;
        off += (bytes + 255) & ~(size_t)255;
        return p;
    };
    int* rowptr = (int*)alloc((NN + 1) * sizeof(int));
    int* cursor = (int*)alloc(NN * sizeof(int));
    int* cnt    = (int*)alloc(SCB * 256 * sizeof(int));
    int* loc    = (int*)alloc(SCB * 256 * sizeof(int));
    int* bsum   = (int*)alloc(SCB * sizeof(int));
    int* boff   = (int*)alloc(SCB * sizeof(int));
    unsigned short* ssrc = (unsigned short*)alloc(NE * sizeof(unsigned short));
    unsigned short* feat16 = (unsigned short*)alloc((size_t)NN * 256 * sizeof(unsigned short));
    unsigned short* hbuf   = (unsigned short*)alloc((size_t)NN * 256 * sizeof(unsigned short));
    float* el   = (float*)alloc((size_t)NN * 4 * sizeof(float));
    float* er   = (float*)alloc((size_t)NN * 4 * sizeof(float));
    unsigned short* Wfrag1  = (unsigned short*)alloc(65536 * sizeof(unsigned short));
    unsigned short* Wfrag2  = (unsigned short*)alloc(65536 * sizeof(unsigned short));
    unsigned short* wlrfrag = (unsigned short*)alloc(4096 * sizeof(unsigned short));
    float* offlr   = (float*)alloc(16 * sizeof(float));
    float* cvec    = (float*)alloc(256 * sizeof(float));
    float* pbuf    = (float*)alloc(256 * 512 * sizeof(float));
    float* bnscale = (float*)alloc(256 * sizeof(float));
    float* bnshift = (float*)alloc(256 * sizeof(float));

    // CSR build (graph identical for all layers)
    hipMemsetAsync(cnt, 0, NN * sizeof(int), stream);
    k_hist<<<(NE + 255) / 256, 256, 0, stream>>>(dst, cnt);
    k_scan1<<<SCB, 256, 0, stream>>>(cnt, loc, bsum);
    k_scan2<<<1, 256, 0, stream>>>(bsum, boff, rowptr);
    k_scan3<<<SCB, 256, 0, stream>>>(loc, boff, rowptr, cursor);
    k_scatter<<<(NE + 255) / 256, 256, 0, stream>>>(src, dst, cursor, ssrc);
    k_fold<<<40, 256, 0, stream>>>(W1, nullptr, nullptr, al1, ar1,
                                   Wfrag1, nullptr, wlrfrag, offlr, 0);

    const int GB = (NN + 63) / 64;  // 782
    const int NB = NN / 4;          // 12500

    // ---- layer 1 ----
    k_gemm<<<GB, 256, 0, stream>>>(x, 1, Wfrag1, nullptr, wlrfrag, offlr, feat16, el, er);
    k_agg<<<NB, 256, 0, stream>>>(feat16, el, er, rowptr, ssrc, nullptr, x,
                                  nullptr, nullptr, 0, b1, 1, hbuf, nullptr, 0);
    k_bnstats<<<256, 256, 0, stream>>>(hbuf, pbuf);
    k_bnfinal<<<1, 256, 0, stream>>>(pbuf, g1, be1, bnscale, bnshift);
    k_fold<<<296, 256, 0, stream>>>(W2, bnscale, bnshift, al2, ar2,
                                    Wfrag2, cvec, wlrfrag, offlr, 1);

    // ---- layer 2 ----
    k_gemm<<<GB, 256, 0, stream>>>(hbuf, 0, Wfrag2, cvec, wlrfrag, offlr, feat16, el, er);
    k_agg<<<NB, 256, 0, stream>>>(feat16, el, er, rowptr, ssrc, hbuf, nullptr,
                                  bnscale, bnshift, 1, b2, 1, hbuf, nullptr, 0);
    k_bnstats<<<256, 256, 0, stream>>>(hbuf, pbuf);
    k_bnfinal<<<1, 256, 0, stream>>>(pbuf, g2, be2, bnscale, bnshift);
    k_fold<<<296, 256, 0, stream>>>(W3, bnscale, bnshift, al3, ar3,
                                    Wfrag2, cvec, wlrfrag, offlr, 1);

    // ---- layer 3 ----
    k_gemm<<<GB, 256, 0, stream>>>(hbuf, 0, Wfrag2, cvec, wlrfrag, offlr, feat16, el, er);
    k_agg<<<NB, 256, 0, stream>>>(feat16, el, er, rowptr, ssrc, hbuf, nullptr,
                                  bnscale, bnshift, 1, b3, 0, nullptr, out, 1);
}